// Round 1
// baseline (1421.912 us; speedup 1.0000x reference)
//
#include <hip/hip_runtime.h>
#include <math.h>

// ---------------------------------------------------------------------------
// densityPropGRUCell: B=16, IN=U=1024.
// Heavy work: 6x  W^T S W  (batched congruence) via bf16 MFMA GEMM pairs.
// Workspace layout (all offsets 256B aligned), total ~141 MB:
//   Tcm  : bf16 [16][1024 v][2048 k]   (stacked  [S1@U | S2@W], transposed)
//   Sz   : bf16 [16][1024][1024]       Sigma_z
//   Sg   : bf16 [16][1024][1024]       Sigma_r, then sigma_g in place
//   AT   : bf16 [3][1024 u][2048 k]    [U_g^T | W_g^T] per gate
//   sp   : f32  [6][1024]              softplus vectors
//   z,gz,r,gr,h,gh,sr : f32 [16][1024]
//   dA,dBzr,dBh,csr   : f32 [16]
// ---------------------------------------------------------------------------

#define B_  16
#define N_  1024
#define NN_ (1024*1024)

typedef __bf16 bf16x8 __attribute__((ext_vector_type(8)));
typedef float  f32x4  __attribute__((ext_vector_type(4)));

__device__ __forceinline__ unsigned short f2bf(float f) {
  union { float f; unsigned int u; } v; v.f = f;
  unsigned int r = v.u + 0x7fffu + ((v.u >> 16) & 1u);   // RNE
  return (unsigned short)(r >> 16);
}
__device__ __forceinline__ float bf2f(unsigned short h) {
  union { unsigned int u; float f; } v; v.u = ((unsigned int)h) << 16;
  return v.f;
}
__device__ __forceinline__ float f4get(const float4& v, int q) {
  return q == 0 ? v.x : (q == 1 ? v.y : (q == 2 ? v.z : v.w));
}
__device__ __forceinline__ unsigned short u4get(const ushort4& v, int q) {
  return q == 0 ? v.x : (q == 1 ? v.y : (q == 2 ? v.z : v.w));
}

// ---------------------------------------------------------------------------
// 128x128-tile MFMA GEMM, BK=32, 4 waves (each 64x64 via 4x4 16x16x32 frags).
// A: row-major [M][K] (AMODE 0: f32, 1: bf16), batch stride aStride (elems).
// B: "cm" form  [N][K] bf16 (i.e. B^T of the math B), + koffB column offset.
// OMODE 0: store C transposed as bf16 into Tcm[v][2048] at column koffT.
// OMODE 1/2: epilogue  out = act_u*act_v*(acc + (u==v)*(dU[b]*spU[u]+dW[b]*spW[u]))
//            stored bf16 (1) or f32 (2) row-major [b][u][v].
// ---------------------------------------------------------------------------
template<int AMODE, int OMODE>
__global__ __launch_bounds__(256)
void gemm128(const void* __restrict__ Ap, int lda, long aStride,
             const unsigned short* __restrict__ Bcm, int ldb, long bStride, int koffB,
             int K,
             unsigned short* __restrict__ Tout, long tStride, int koffT,
             void* __restrict__ Sout,
             const float* __restrict__ act,
             const float* __restrict__ spU, const float* __restrict__ spW,
             const float* __restrict__ dU, const float* __restrict__ dW)
{
  __shared__ unsigned short Alds[128][40];
  __shared__ unsigned short Blds[128][40];
  const int b     = blockIdx.z;
  const int mbase = blockIdx.x * 128;
  const int nbase = blockIdx.y * 128;
  const int t    = threadIdx.x;
  const int lane = t & 63, wid = t >> 6;
  const int wm = wid >> 1, wc = wid & 1;
  const int cg = t & 7, r0 = t >> 3;

  f32x4 acc[4][4];
  const f32x4 zero4 = {0.f, 0.f, 0.f, 0.f};
#pragma unroll
  for (int i = 0; i < 4; i++)
#pragma unroll
    for (int j = 0; j < 4; j++) acc[i][j] = zero4;

  const float*          Af = (const float*)Ap + (size_t)b * aStride;
  const unsigned short* Ah = (const unsigned short*)Ap + (size_t)b * aStride;
  const unsigned short* Bb = Bcm + (size_t)b * bStride + koffB;

  for (int k0 = 0; k0 < K; k0 += 32) {
#pragma unroll
    for (int p = 0; p < 4; p++) {
      const int row = r0 + p * 32;
      ushort4 hv;
      if (AMODE == 0) {
        const float4 v = *(const float4*)(Af + (size_t)(mbase + row) * lda + k0 + cg * 4);
        hv.x = f2bf(v.x); hv.y = f2bf(v.y); hv.z = f2bf(v.z); hv.w = f2bf(v.w);
      } else {
        hv = *(const ushort4*)(Ah + (size_t)(mbase + row) * lda + k0 + cg * 4);
      }
      *(ushort4*)&Alds[row][cg * 4] = hv;
      const ushort4 bv = *(const ushort4*)(Bb + (size_t)(nbase + row) * ldb + k0 + cg * 4);
      *(ushort4*)&Blds[row][cg * 4] = bv;
    }
    __syncthreads();
    bf16x8 av[4], bv[4];
    const int lrow = lane & 15, lko = (lane >> 4) * 8;
#pragma unroll
    for (int mi = 0; mi < 4; mi++) av[mi] = *(const bf16x8*)&Alds[wm * 64 + mi * 16 + lrow][lko];
#pragma unroll
    for (int ni = 0; ni < 4; ni++) bv[ni] = *(const bf16x8*)&Blds[wc * 64 + ni * 16 + lrow][lko];
#pragma unroll
    for (int mi = 0; mi < 4; mi++)
#pragma unroll
      for (int ni = 0; ni < 4; ni++)
        acc[mi][ni] = __builtin_amdgcn_mfma_f32_16x16x32_bf16(av[mi], bv[ni], acc[mi][ni], 0, 0, 0);
    __syncthreads();
  }

  if (OMODE == 0) {
    unsigned short* T = Tout + (size_t)b * tStride + koffT;
#pragma unroll
    for (int mi = 0; mi < 4; mi++)
#pragma unroll
      for (int ni = 0; ni < 4; ni++) {
        const int i0 = mbase + wm * 64 + mi * 16 + (lane >> 4) * 4;
        const int v  = nbase + wc * 64 + ni * 16 + (lane & 15);
        ushort4 pk;
        pk.x = f2bf(acc[mi][ni][0]); pk.y = f2bf(acc[mi][ni][1]);
        pk.z = f2bf(acc[mi][ni][2]); pk.w = f2bf(acc[mi][ni][3]);
        *(ushort4*)(T + (size_t)v * 2048 + i0) = pk;
      }
  } else {
    const float* actb = act + b * N_;
    const float dUb = dU[b], dWb = dW[b];
#pragma unroll
    for (int mi = 0; mi < 4; mi++)
#pragma unroll
      for (int ni = 0; ni < 4; ni++) {
        const int ub = mbase + wm * 64 + mi * 16 + (lane >> 4) * 4;
        const int v  = nbase + wc * 64 + ni * 16 + (lane & 15);
        const float avx = actb[v];
#pragma unroll
        for (int r = 0; r < 4; r++) {
          const int u = ub + r;
          float val = acc[mi][ni][r];
          if (u == v) val += dUb * spU[u] + dWb * spW[u];
          val *= actb[u] * avx;
          if (OMODE == 1)
            ((unsigned short*)Sout)[(size_t)b * NN_ + (size_t)u * N_ + v] = f2bf(val);
          else
            ((float*)Sout)[(size_t)b * NN_ + (size_t)u * N_ + v] = val;
        }
      }
  }
}

// --------------------------- small kernels ---------------------------------

// AT_g[u][k] = (k<1024 ? U_g[k][u] : W_g[k-1024][u]) as bf16. grid(32,64,3).
__global__ void build_AT(const float* __restrict__ Uz, const float* __restrict__ Wz,
                         const float* __restrict__ Ur, const float* __restrict__ Wr,
                         const float* __restrict__ Uh, const float* __restrict__ Wh,
                         unsigned short* __restrict__ AT)
{
  __shared__ float tile[32][33];
  const int g = blockIdx.z;
  const float* U = g == 0 ? Uz : (g == 1 ? Ur : Uh);
  const float* W = g == 0 ? Wz : (g == 1 ? Wr : Wh);
  const int u0  = blockIdx.x * 32;
  const int k0g = blockIdx.y * 32;
  const float* src = (k0g >= 1024) ? W : U;
  const int kloc = k0g & 1023;
  const int tx = threadIdx.x & 31, ty = threadIdx.x >> 5;
  unsigned short* out = AT + (size_t)g * N_ * 2048;
#pragma unroll
  for (int i = 0; i < 32; i += 8) tile[ty + i][tx] = src[(size_t)(kloc + ty + i) * N_ + u0 + tx];
  __syncthreads();
#pragma unroll
  for (int i = 0; i < 32; i += 8)
    out[(size_t)(u0 + ty + i) * 2048 + k0g + tx] = f2bf(tile[tx][ty + i]);
}

__global__ void softplus6(const float* a0, const float* a1, const float* a2,
                          const float* a3, const float* a4, const float* a5,
                          float* __restrict__ sp)
{
  const float* src[6] = {a0, a1, a2, a3, a4, a5};
  const int g = blockIdx.x;
  const float* s = src[g];
  for (int i = threadIdx.x; i < N_; i += 256) {
    float x = s[i];
    sp[g * N_ + i] = (x > 20.f) ? x : log1pf(expf(x));
  }
}

// dA[b] = sum mu^2 + tr(sigma_in);  dBzr[b] = sum prev^2 + tr(Sigma_state)
__global__ void scalars1(const float* __restrict__ mu, const float* __restrict__ prev,
                         const float* __restrict__ sin_, const float* __restrict__ Sst,
                         float* __restrict__ dA, float* __restrict__ dBzr)
{
  __shared__ float red[256];
  const int b = blockIdx.x;
  float s1 = 0.f, s2 = 0.f;
  for (int i = threadIdx.x; i < N_; i += 256) {
    const float m = mu[b * N_ + i];
    s1 += m * m + sin_[(size_t)b * NN_ + (size_t)i * (N_ + 1)];
    const float p = prev[b * N_ + i];
    s2 += p * p + Sst[(size_t)b * NN_ + (size_t)i * (N_ + 1)];
  }
  red[threadIdx.x] = s1; __syncthreads();
  for (int s = 128; s > 0; s >>= 1) { if (threadIdx.x < s) red[threadIdx.x] += red[threadIdx.x + s]; __syncthreads(); }
  if (threadIdx.x == 0) dA[b] = red[0];
  __syncthreads();
  red[threadIdx.x] = s2; __syncthreads();
  for (int s = 128; s > 0; s >>= 1) { if (threadIdx.x < s) red[threadIdx.x] += red[threadIdx.x + s]; __syncthreads(); }
  if (threadIdx.x == 0) dBzr[b] = red[0];
}

// pre = x1@U + x2@W ; ACT 0: sigmoid (g=s(1-s)), 1: tanh (g=1-s^2). grid 16.
template<int ACT>
__global__ void gate_gemm(const float* __restrict__ x1, const float* __restrict__ x2,
                          const float* __restrict__ U, const float* __restrict__ W,
                          float* __restrict__ outS, float* __restrict__ outG)
{
  const int col = blockIdx.x * 64 + (threadIdx.x & 63);
  const int q = threadIdx.x >> 6;
  float acc[4] = {0.f, 0.f, 0.f, 0.f};
  for (int k = 0; k < N_; k++) {
    const float wu = U[(size_t)k * N_ + col];
    const float ww = W[(size_t)k * N_ + col];
#pragma unroll
    for (int bb = 0; bb < 4; bb++) {
      const int b = q * 4 + bb;
      acc[bb] += x1[b * N_ + k] * wu + x2[b * N_ + k] * ww;
    }
  }
#pragma unroll
  for (int bb = 0; bb < 4; bb++) {
    const int b = q * 4 + bb;
    float s, g;
    if (ACT == 0) { s = 1.f / (1.f + expf(-acc[bb])); g = s * (1.f - s); }
    else          { s = tanhf(acc[bb]);               g = 1.f - s * s;   }
    outS[b * N_ + col] = s;
    outG[b * N_ + col] = g;
  }
}

__global__ void sr_csr(const float* __restrict__ prev, const float* __restrict__ r,
                       float* __restrict__ sr, float* __restrict__ csr)
{
  __shared__ float red[256];
  const int b = blockIdx.x;
  float s = 0.f;
  for (int i = threadIdx.x; i < N_; i += 256) {
    const float v = prev[b * N_ + i] * r[b * N_ + i];
    sr[b * N_ + i] = v;
    s += v * v;
  }
  red[threadIdx.x] = s; __syncthreads();
  for (int k = 128; k > 0; k >>= 1) { if (threadIdx.x < k) red[threadIdx.x] += red[threadIdx.x + k]; __syncthreads(); }
  if (threadIdx.x == 0) csr[b] = red[0];
}

// sigma_g = Sst.*Sr + p_i p_j Sr + r_i r_j Sst   (in place over Sr, bf16)
__global__ void hadamard_sg(const float* __restrict__ Sst, unsigned short* __restrict__ Sg,
                            const float* __restrict__ prev, const float* __restrict__ r)
{
  const size_t idx = ((size_t)blockIdx.x * 256 + threadIdx.x) * 4;
  const int b = (int)(idx >> 20);
  const int rem = (int)(idx & (NN_ - 1));
  const int i = rem >> 10, j0 = rem & 1023;
  const float pi = prev[b * N_ + i], ri = r[b * N_ + i];
  const float4  ss  = *(const float4*)(Sst + (size_t)b * NN_ + rem);
  const ushort4 sr4 = *(const ushort4*)(Sg + (size_t)b * NN_ + rem);
  ushort4 o;
  unsigned short* op = (unsigned short*)&o;
#pragma unroll
  for (int q = 0; q < 4; q++) {
    const float srv = bf2f(u4get(sr4, q));
    const float stv = f4get(ss, q);
    const float pj = prev[b * N_ + j0 + q];
    const float rj = r[b * N_ + j0 + q];
    op[q] = f2bf(stv * srv + pi * pj * srv + ri * rj * stv);
  }
  *(ushort4*)(Sg + (size_t)b * NN_ + rem) = o;
}

// dBh[b] = csr[b] + tr(sigma_g[b])
__global__ void scalars2(const unsigned short* __restrict__ Sg,
                         const float* __restrict__ csr, float* __restrict__ dBh)
{
  __shared__ float red[256];
  const int b = blockIdx.x;
  float s = 0.f;
  for (int i = threadIdx.x; i < N_; i += 256)
    s += bf2f(Sg[(size_t)b * NN_ + (size_t)i * (N_ + 1)]);
  red[threadIdx.x] = s; __syncthreads();
  for (int k = 128; k > 0; k >>= 1) { if (threadIdx.x < k) red[threadIdx.x] += red[threadIdx.x + k]; __syncthreads(); }
  if (threadIdx.x == 0) dBh[b] = red[0] + csr[b];
}

__global__ void mu_kernel(const float* __restrict__ z, const float* __restrict__ prev,
                          const float* __restrict__ h, float* __restrict__ mu_out)
{
  const int i = blockIdx.x * 256 + threadIdx.x;
  const float zz = z[i];
  mu_out[i] = zz * prev[i] + (1.f - zz) * h[i];
}

// Sigma_out = a + b - ab - abT, in place over SigOut (which holds Sigma_h).
__global__ void combine(const unsigned short* __restrict__ Sz, const float* __restrict__ Sst,
                        const float* __restrict__ z, const float* __restrict__ prev,
                        const float* __restrict__ h, float* __restrict__ SigOut)
{
  const int row = blockIdx.x;                 // 0..16383 = (b,u)
  const int b = row >> 10, u = row & 1023;
  const float zu = z[b * N_ + u], pu = prev[b * N_ + u], hu = h[b * N_ + u];
  const size_t base = (size_t)b * NN_ + (size_t)u * N_;
  const int j0 = threadIdx.x * 4;
  const ushort4 s4 = *(const ushort4*)(Sz + base + j0);
  const float4 sh = *(const float4*)(SigOut + base + j0);
  const float4 st = *(const float4*)(Sst + base + j0);
  const float4 zv = *(const float4*)(z + b * N_ + j0);
  const float4 pv = *(const float4*)(prev + b * N_ + j0);
  const float4 hv = *(const float4*)(h + b * N_ + j0);
  float o[4];
#pragma unroll
  for (int q = 0; q < 4; q++) {
    const int v = j0 + q;
    const float sz  = bf2f(u4get(s4, q));
    const float shh = f4get(sh, q);
    const float stt = f4get(st, q);
    const float zvv = f4get(zv, q);
    const float pvv = f4get(pv, q);
    const float hvv = f4get(hv, q);
    float res = sz * stt + zu * zvv * stt + pu * pvv * sz
              + sz * shh + (1.f - zu) * (1.f - zvv) * shh + hu * hvv * sz
              - sz * (pu * hvv) - sz * (hu * pvv);
    if (!isfinite(res)) res = 0.f;
    if (u == v) res = fabsf(res);
    o[q] = res;
  }
  float4 ov; ov.x = o[0]; ov.y = o[1]; ov.z = o[2]; ov.w = o[3];
  *(float4*)(SigOut + base + j0) = ov;
}

// ---------------------------------------------------------------------------

extern "C" void kernel_launch(void* const* d_in, const int* in_sizes, int n_in,
                              void* d_out, int out_size, void* d_ws, size_t ws_size,
                              hipStream_t stream)
{
  const float* mu   = (const float*)d_in[0];
  const float* sin_ = (const float*)d_in[1];
  const float* prev = (const float*)d_in[2];
  const float* Sst  = (const float*)d_in[3];
  const float* Uz = (const float*)d_in[4];  const float* uzs = (const float*)d_in[5];
  const float* Wz = (const float*)d_in[6];  const float* wzs = (const float*)d_in[7];
  const float* Ur = (const float*)d_in[8];  const float* urs = (const float*)d_in[9];
  const float* Wr = (const float*)d_in[10]; const float* wrs = (const float*)d_in[11];
  const float* Uh = (const float*)d_in[12]; const float* uhs = (const float*)d_in[13];
  const float* Wh = (const float*)d_in[14]; const float* whs = (const float*)d_in[15];

  char* ws = (char*)d_ws;
  size_t off = 0;
  auto take = [&](size_t bytes) -> char* {
    char* p = ws + off;
    off = (off + bytes + 255) & ~(size_t)255;
    return p;
  };
  unsigned short* Tcm = (unsigned short*)take((size_t)B_ * 2048 * 1024 * 2); // 64 MB
  unsigned short* Sz  = (unsigned short*)take((size_t)B_ * NN_ * 2);        // 32 MB
  unsigned short* Sg  = (unsigned short*)take((size_t)B_ * NN_ * 2);        // 32 MB
  unsigned short* AT  = (unsigned short*)take((size_t)3 * N_ * 2048 * 2);   // 12 MB
  float* sp   = (float*)take(6 * N_ * 4);
  float* z    = (float*)take(B_ * N_ * 4);
  float* gz   = (float*)take(B_ * N_ * 4);
  float* rr   = (float*)take(B_ * N_ * 4);
  float* gr   = (float*)take(B_ * N_ * 4);
  float* h    = (float*)take(B_ * N_ * 4);
  float* gh   = (float*)take(B_ * N_ * 4);
  float* sr   = (float*)take(B_ * N_ * 4);
  float* dA   = (float*)take(64);
  float* dBzr = (float*)take(64);
  float* dBh  = (float*)take(64);
  float* csr  = (float*)take(64);
  if (off > ws_size) return;  // workspace too small (needs ~141 MB)

  float* mu_out = (float*)d_out;
  float* SigOut = (float*)d_out + (size_t)B_ * N_;

  const unsigned short* ATz = AT;
  const unsigned short* ATr = AT + (size_t)N_ * 2048;
  const unsigned short* ATh = AT + (size_t)2 * N_ * 2048;

  // ---- prep ----
  softplus6<<<6, 256, 0, stream>>>(uzs, wzs, urs, wrs, uhs, whs, sp);
  scalars1<<<16, 256, 0, stream>>>(mu, prev, sin_, Sst, dA, dBzr);
  build_AT<<<dim3(32, 64, 3), 256, 0, stream>>>(Uz, Wz, Ur, Wr, Uh, Wh, AT);
  gate_gemm<0><<<16, 256, 0, stream>>>(mu, prev, Uz, Wz, z, gz);
  gate_gemm<0><<<16, 256, 0, stream>>>(mu, prev, Ur, Wr, rr, gr);
  sr_csr<<<16, 256, 0, stream>>>(prev, rr, sr, csr);
  gate_gemm<1><<<16, 256, 0, stream>>>(mu, sr, Uh, Wh, h, gh);

  const dim3 gg(8, 8, 16);
  const long tS = (long)2048 * 1024;

  // ---- z gate ----
  gemm128<0, 0><<<gg, 256, 0, stream>>>(sin_, 1024, (long)NN_, ATz, 2048, 0, 0,    1024,
                                        Tcm, tS, 0,    nullptr, nullptr, nullptr, nullptr, nullptr, nullptr);
  gemm128<0, 0><<<gg, 256, 0, stream>>>(Sst,  1024, (long)NN_, ATz, 2048, 0, 1024, 1024,
                                        Tcm, tS, 1024, nullptr, nullptr, nullptr, nullptr, nullptr, nullptr);
  gemm128<1, 1><<<gg, 256, 0, stream>>>(ATz, 2048, 0, Tcm, 2048, tS, 0, 2048,
                                        nullptr, 0, 0, Sz, gz, sp + 0, sp + 1024, dA, dBzr);
  // ---- r gate ----
  gemm128<0, 0><<<gg, 256, 0, stream>>>(sin_, 1024, (long)NN_, ATr, 2048, 0, 0,    1024,
                                        Tcm, tS, 0,    nullptr, nullptr, nullptr, nullptr, nullptr, nullptr);
  gemm128<0, 0><<<gg, 256, 0, stream>>>(Sst,  1024, (long)NN_, ATr, 2048, 0, 1024, 1024,
                                        Tcm, tS, 1024, nullptr, nullptr, nullptr, nullptr, nullptr, nullptr);
  gemm128<1, 1><<<gg, 256, 0, stream>>>(ATr, 2048, 0, Tcm, 2048, tS, 0, 2048,
                                        nullptr, 0, 0, Sg, gr, sp + 2048, sp + 3072, dA, dBzr);
  // ---- sigma_g (in place over Sg) ----
  hadamard_sg<<<16384, 256, 0, stream>>>(Sst, Sg, prev, rr);
  scalars2<<<16, 256, 0, stream>>>(Sg, csr, dBh);
  // ---- h gate ----
  gemm128<0, 0><<<gg, 256, 0, stream>>>(sin_, 1024, (long)NN_, ATh, 2048, 0, 0,    1024,
                                        Tcm, tS, 0,    nullptr, nullptr, nullptr, nullptr, nullptr, nullptr);
  gemm128<1, 0><<<gg, 256, 0, stream>>>(Sg,   1024, (long)NN_, ATh, 2048, 0, 1024, 1024,
                                        Tcm, tS, 1024, nullptr, nullptr, nullptr, nullptr, nullptr, nullptr);
  gemm128<1, 2><<<gg, 256, 0, stream>>>(ATh, 2048, 0, Tcm, 2048, tS, 0, 2048,
                                        nullptr, 0, 0, SigOut, gh, sp + 4096, sp + 5120, dA, dBh);
  // ---- combine ----
  mu_kernel<<<64, 256, 0, stream>>>(z, prev, h, mu_out);
  combine<<<16384, 256, 0, stream>>>(Sz, Sst, z, prev, h, SigOut);
}

// Round 2
// 1274.955 us; speedup vs baseline: 1.1153x; 1.1153x over previous
//
#include <hip/hip_runtime.h>
#include <math.h>

// ---------------------------------------------------------------------------
// densityPropGRUCell: B=16, IN=U=1024.
// All heavy GEMMs all-bf16 with global_load_lds (m97 structure).
// Stage 1 per gate computes Tcm[v][i] = sum_j AT[v][j] * S[i][j]  (coalesced)
// Stage 2 computes Sigma[u][v] = sum_k AT[u][k] * Tcm[v][k] + diag, scaled.
// Workspace (~141 MB): Tcm 64 | Sz 32 | Sg 32 | AT 12 | vectors.
// SinH/SstH (bf16 copies of sigma_inputs / Sigma_state) live in d_out's
// SigOut region, which is only written by the h-gate stage-2 at the end.
// ---------------------------------------------------------------------------

#define B_  16
#define N_  1024
#define NN_ (1024*1024)

typedef __bf16 bf16x8 __attribute__((ext_vector_type(8)));
typedef float  f32x4  __attribute__((ext_vector_type(4)));

__device__ __forceinline__ unsigned short f2bf(float f) {
  union { float f; unsigned int u; } v; v.f = f;
  unsigned int r = v.u + 0x7fffu + ((v.u >> 16) & 1u);   // RNE
  return (unsigned short)(r >> 16);
}
__device__ __forceinline__ float bf2f(unsigned short h) {
  union { unsigned int u; float f; } v; v.u = ((unsigned int)h) << 16;
  return v.f;
}
__device__ __forceinline__ float f4get(const float4& v, int q) {
  return q == 0 ? v.x : (q == 1 ? v.y : (q == 2 ? v.z : v.w));
}
__device__ __forceinline__ unsigned short u4get(const ushort4& v, int q) {
  return q == 0 ? v.x : (q == 1 ? v.y : (q == 2 ? v.z : v.w));
}

__device__ __forceinline__ void gload_lds16(const void* g, void* l) {
  __builtin_amdgcn_global_load_lds((__attribute__((address_space(1))) void*)g,
                                   (__attribute__((address_space(3))) void*)l,
                                   16, 0, 0);
}

// ---------------------------------------------------------------------------
// 128x128-tile bf16 MFMA GEMM, BK=32, 4 waves (each 64x64 via 4x4 16x16x32).
//   D[m][n] = sum_k A[m][koffA + k] * B[n][k]
// A: bf16 [.. ][lda], batch stride aStride (0 = shared), column offset koffA.
// B: bf16 [..][ldb], batch stride bStride.
// OMODE 0: raw bf16 store at Out[b*oStride + m*ldo + noff + n].
// OMODE 1/2: out = act_m*act_n*(acc + (m==n)*(dU[b]*spU[m]+dW[b]*spW[m]))
//            stored bf16 (1) or f32 (2) at Out[b*oStride + m*ldo + n].
// ---------------------------------------------------------------------------
template<int OMODE>
__global__ __launch_bounds__(256)
void gemm_bt(const unsigned short* __restrict__ A, int lda, long aStride, int koffA,
             const unsigned short* __restrict__ Bm, int ldb, long bStride,
             int K,
             void* __restrict__ Out, int ldo, long oStride, int noff,
             const float* __restrict__ act,
             const float* __restrict__ spU, const float* __restrict__ spW,
             const float* __restrict__ dU, const float* __restrict__ dW)
{
  __shared__ unsigned short Alds[4096];   // [128 rows][32 k] linear
  __shared__ unsigned short Blds[4096];
  const int b = blockIdx.z;
  const int mbase = blockIdx.x * 128, nbase = blockIdx.y * 128;
  const int t = threadIdx.x, lane = t & 63, w = t >> 6;
  const int wm = w >> 1, wc = w & 1;

  f32x4 acc[4][4];
  const f32x4 zero4 = {0.f, 0.f, 0.f, 0.f};
#pragma unroll
  for (int i = 0; i < 4; i++)
#pragma unroll
    for (int j = 0; j < 4; j++) acc[i][j] = zero4;

  // staging: each wave's 64 lanes cover 16 rows x 32 k (1 KiB) per issue
  const int srow = (w << 4) + (lane >> 2);      // wave-local 16-row panel
  const int scol = (lane & 3) << 3;             // 4 lanes x 8 bf16 = one row of BK
  const unsigned short* Ag = A + (size_t)b * aStride + (size_t)(mbase + srow) * lda + koffA + scol;
  const unsigned short* Bg = Bm + (size_t)b * bStride + (size_t)(nbase + srow) * ldb + scol;
  unsigned short* As0 = Alds + (w << 9);        // wave-uniform LDS bases
  unsigned short* As1 = Alds + 2048 + (w << 9);
  unsigned short* Bs0 = Blds + (w << 9);
  unsigned short* Bs1 = Blds + 2048 + (w << 9);
  const size_t a64 = (size_t)64 * lda, b64 = (size_t)64 * ldb;

  for (int k0 = 0; k0 < K; k0 += 32) {
    gload_lds16(Ag + k0,       As0);
    gload_lds16(Ag + k0 + a64, As1);
    gload_lds16(Bg + k0,       Bs0);
    gload_lds16(Bg + k0 + b64, Bs1);
    __syncthreads();
    const int lrow = lane & 15;
    const int lko  = (lane >> 4) << 3;
    bf16x8 av[4], bv[4];
#pragma unroll
    for (int mi = 0; mi < 4; mi++)
      av[mi] = *(const bf16x8*)&Alds[(wm * 64 + mi * 16 + lrow) * 32 + lko];
#pragma unroll
    for (int ni = 0; ni < 4; ni++)
      bv[ni] = *(const bf16x8*)&Blds[(wc * 64 + ni * 16 + lrow) * 32 + lko];
#pragma unroll
    for (int mi = 0; mi < 4; mi++)
#pragma unroll
      for (int ni = 0; ni < 4; ni++)
        acc[mi][ni] = __builtin_amdgcn_mfma_f32_16x16x32_bf16(av[mi], bv[ni], acc[mi][ni], 0, 0, 0);
    __syncthreads();
  }

  if (OMODE == 0) {
    unsigned short* O = (unsigned short*)Out + (size_t)b * oStride + noff;
#pragma unroll
    for (int mi = 0; mi < 4; mi++) {
      const int row0 = mbase + wm * 64 + mi * 16 + ((lane >> 4) << 2);
#pragma unroll
      for (int ni = 0; ni < 4; ni++) {
        const int col = nbase + wc * 64 + ni * 16 + (lane & 15);
#pragma unroll
        for (int r = 0; r < 4; r++)
          O[(size_t)(row0 + r) * ldo + col] = f2bf(acc[mi][ni][r]);
      }
    }
  } else {
    const float* actb = act + b * N_;
    const float dUb = dU[b], dWb = dW[b];
#pragma unroll
    for (int mi = 0; mi < 4; mi++) {
      const int row0 = mbase + wm * 64 + mi * 16 + ((lane >> 4) << 2);
#pragma unroll
      for (int ni = 0; ni < 4; ni++) {
        const int v = nbase + wc * 64 + ni * 16 + (lane & 15);
        const float av = actb[v];
#pragma unroll
        for (int r = 0; r < 4; r++) {
          const int u = row0 + r;
          float val = acc[mi][ni][r];
          if (u == v) val += dUb * spU[u] + dWb * spW[u];
          val *= actb[u] * av;
          if (OMODE == 1)
            ((unsigned short*)Out)[(size_t)b * oStride + (size_t)u * ldo + v] = f2bf(val);
          else
            ((float*)Out)[(size_t)b * oStride + (size_t)u * ldo + v] = val;
        }
      }
    }
  }
}

// --------------------------- small kernels ---------------------------------

__global__ void conv_bf16(const float* __restrict__ in, unsigned short* __restrict__ out, int n4)
{
  int i = blockIdx.x * 256 + threadIdx.x;
  const int stride = gridDim.x * 256;
  for (; i < n4; i += stride) {
    const float4 v = ((const float4*)in)[i];
    ushort4 o;
    o.x = f2bf(v.x); o.y = f2bf(v.y); o.z = f2bf(v.z); o.w = f2bf(v.w);
    ((ushort4*)out)[i] = o;
  }
}

// AT_g[u][k] = (k<1024 ? U_g[k][u] : W_g[k-1024][u]) as bf16. grid(32,64,3).
__global__ void build_AT(const float* __restrict__ Uz, const float* __restrict__ Wz,
                         const float* __restrict__ Ur, const float* __restrict__ Wr,
                         const float* __restrict__ Uh, const float* __restrict__ Wh,
                         unsigned short* __restrict__ AT)
{
  __shared__ float tile[32][33];
  const int g = blockIdx.z;
  const float* U = g == 0 ? Uz : (g == 1 ? Ur : Uh);
  const float* W = g == 0 ? Wz : (g == 1 ? Wr : Wh);
  const int u0  = blockIdx.x * 32;
  const int k0g = blockIdx.y * 32;
  const float* src = (k0g >= 1024) ? W : U;
  const int kloc = k0g & 1023;
  const int tx = threadIdx.x & 31, ty = threadIdx.x >> 5;
  unsigned short* out = AT + (size_t)g * N_ * 2048;
#pragma unroll
  for (int i = 0; i < 32; i += 8) tile[ty + i][tx] = src[(size_t)(kloc + ty + i) * N_ + u0 + tx];
  __syncthreads();
#pragma unroll
  for (int i = 0; i < 32; i += 8)
    out[(size_t)(u0 + ty + i) * 2048 + k0g + tx] = f2bf(tile[tx][ty + i]);
}

__global__ void softplus6(const float* a0, const float* a1, const float* a2,
                          const float* a3, const float* a4, const float* a5,
                          float* __restrict__ sp)
{
  const float* src[6] = {a0, a1, a2, a3, a4, a5};
  const int g = blockIdx.x;
  const float* s = src[g];
  for (int i = threadIdx.x; i < N_; i += 256) {
    float x = s[i];
    sp[g * N_ + i] = (x > 20.f) ? x : log1pf(expf(x));
  }
}

__global__ void scalars1(const float* __restrict__ mu, const float* __restrict__ prev,
                         const float* __restrict__ sin_, const float* __restrict__ Sst,
                         float* __restrict__ dA, float* __restrict__ dBzr)
{
  __shared__ float red[256];
  const int b = blockIdx.x;
  float s1 = 0.f, s2 = 0.f;
  for (int i = threadIdx.x; i < N_; i += 256) {
    const float m = mu[b * N_ + i];
    s1 += m * m + sin_[(size_t)b * NN_ + (size_t)i * (N_ + 1)];
    const float p = prev[b * N_ + i];
    s2 += p * p + Sst[(size_t)b * NN_ + (size_t)i * (N_ + 1)];
  }
  red[threadIdx.x] = s1; __syncthreads();
  for (int s = 128; s > 0; s >>= 1) { if (threadIdx.x < s) red[threadIdx.x] += red[threadIdx.x + s]; __syncthreads(); }
  if (threadIdx.x == 0) dA[b] = red[0];
  __syncthreads();
  red[threadIdx.x] = s2; __syncthreads();
  for (int s = 128; s > 0; s >>= 1) { if (threadIdx.x < s) red[threadIdx.x] += red[threadIdx.x + s]; __syncthreads(); }
  if (threadIdx.x == 0) dBzr[b] = red[0];
}

// pre = x1@U + x2@W ; ACT 0: sigmoid (g=s(1-s)), 1: tanh (g=1-s^2). grid 16.
template<int ACT>
__global__ void gate_gemm(const float* __restrict__ x1, const float* __restrict__ x2,
                          const float* __restrict__ U, const float* __restrict__ W,
                          float* __restrict__ outS, float* __restrict__ outG)
{
  const int col = blockIdx.x * 64 + (threadIdx.x & 63);
  const int q = threadIdx.x >> 6;
  float acc[4] = {0.f, 0.f, 0.f, 0.f};
  for (int k = 0; k < N_; k++) {
    const float wu = U[(size_t)k * N_ + col];
    const float ww = W[(size_t)k * N_ + col];
#pragma unroll
    for (int bb = 0; bb < 4; bb++) {
      const int b = q * 4 + bb;
      acc[bb] += x1[b * N_ + k] * wu + x2[b * N_ + k] * ww;
    }
  }
#pragma unroll
  for (int bb = 0; bb < 4; bb++) {
    const int b = q * 4 + bb;
    float s, g;
    if (ACT == 0) { s = 1.f / (1.f + expf(-acc[bb])); g = s * (1.f - s); }
    else          { s = tanhf(acc[bb]);               g = 1.f - s * s;   }
    outS[b * N_ + col] = s;
    outG[b * N_ + col] = g;
  }
}

__global__ void sr_csr(const float* __restrict__ prev, const float* __restrict__ r,
                       float* __restrict__ sr, float* __restrict__ csr)
{
  __shared__ float red[256];
  const int b = blockIdx.x;
  float s = 0.f;
  for (int i = threadIdx.x; i < N_; i += 256) {
    const float v = prev[b * N_ + i] * r[b * N_ + i];
    sr[b * N_ + i] = v;
    s += v * v;
  }
  red[threadIdx.x] = s; __syncthreads();
  for (int k = 128; k > 0; k >>= 1) { if (threadIdx.x < k) red[threadIdx.x] += red[threadIdx.x + k]; __syncthreads(); }
  if (threadIdx.x == 0) csr[b] = red[0];
}

// sigma_g = Sst.*Sr + p_i p_j Sr + r_i r_j Sst   (in place over Sr, bf16)
__global__ void hadamard_sg(const float* __restrict__ Sst, unsigned short* __restrict__ Sg,
                            const float* __restrict__ prev, const float* __restrict__ r)
{
  const size_t idx = ((size_t)blockIdx.x * 256 + threadIdx.x) * 4;
  const int b = (int)(idx >> 20);
  const int rem = (int)(idx & (NN_ - 1));
  const int i = rem >> 10, j0 = rem & 1023;
  const float pi = prev[b * N_ + i], ri = r[b * N_ + i];
  const float4  ss  = *(const float4*)(Sst + (size_t)b * NN_ + rem);
  const ushort4 sr4 = *(const ushort4*)(Sg + (size_t)b * NN_ + rem);
  ushort4 o;
  unsigned short* op = (unsigned short*)&o;
#pragma unroll
  for (int q = 0; q < 4; q++) {
    const float srv = bf2f(u4get(sr4, q));
    const float stv = f4get(ss, q);
    const float pj = prev[b * N_ + j0 + q];
    const float rj = r[b * N_ + j0 + q];
    op[q] = f2bf(stv * srv + pi * pj * srv + ri * rj * stv);
  }
  *(ushort4*)(Sg + (size_t)b * NN_ + rem) = o;
}

__global__ void scalars2(const unsigned short* __restrict__ Sg,
                         const float* __restrict__ csr, float* __restrict__ dBh)
{
  __shared__ float red[256];
  const int b = blockIdx.x;
  float s = 0.f;
  for (int i = threadIdx.x; i < N_; i += 256)
    s += bf2f(Sg[(size_t)b * NN_ + (size_t)i * (N_ + 1)]);
  red[threadIdx.x] = s; __syncthreads();
  for (int k = 128; k > 0; k >>= 1) { if (threadIdx.x < k) red[threadIdx.x] += red[threadIdx.x + k]; __syncthreads(); }
  if (threadIdx.x == 0) dBh[b] = red[0] + csr[b];
}

__global__ void mu_kernel(const float* __restrict__ z, const float* __restrict__ prev,
                          const float* __restrict__ h, float* __restrict__ mu_out)
{
  const int i = blockIdx.x * 256 + threadIdx.x;
  const float zz = z[i];
  mu_out[i] = zz * prev[i] + (1.f - zz) * h[i];
}

// Sigma_out = a + b - ab - abT, in place over SigOut (which holds Sigma_h).
__global__ void combine(const unsigned short* __restrict__ Sz, const float* __restrict__ Sst,
                        const float* __restrict__ z, const float* __restrict__ prev,
                        const float* __restrict__ h, float* __restrict__ SigOut)
{
  const int row = blockIdx.x;                 // 0..16383 = (b,u)
  const int b = row >> 10, u = row & 1023;
  const float zu = z[b * N_ + u], pu = prev[b * N_ + u], hu = h[b * N_ + u];
  const size_t base = (size_t)b * NN_ + (size_t)u * N_;
  const int j0 = threadIdx.x * 4;
  const ushort4 s4 = *(const ushort4*)(Sz + base + j0);
  const float4 sh = *(const float4*)(SigOut + base + j0);
  const float4 st = *(const float4*)(Sst + base + j0);
  const float4 zv = *(const float4*)(z + b * N_ + j0);
  const float4 pv = *(const float4*)(prev + b * N_ + j0);
  const float4 hv = *(const float4*)(h + b * N_ + j0);
  float o[4];
#pragma unroll
  for (int q = 0; q < 4; q++) {
    const int v = j0 + q;
    const float sz  = bf2f(u4get(s4, q));
    const float shh = f4get(sh, q);
    const float stt = f4get(st, q);
    const float zvv = f4get(zv, q);
    const float pvv = f4get(pv, q);
    const float hvv = f4get(hv, q);
    float res = sz * stt + zu * zvv * stt + pu * pvv * sz
              + sz * shh + (1.f - zu) * (1.f - zvv) * shh + hu * hvv * sz
              - sz * (pu * hvv) - sz * (hu * pvv);
    if (!isfinite(res)) res = 0.f;
    if (u == v) res = fabsf(res);
    o[q] = res;
  }
  float4 ov; ov.x = o[0]; ov.y = o[1]; ov.z = o[2]; ov.w = o[3];
  *(float4*)(SigOut + base + j0) = ov;
}

// ---------------------------------------------------------------------------

extern "C" void kernel_launch(void* const* d_in, const int* in_sizes, int n_in,
                              void* d_out, int out_size, void* d_ws, size_t ws_size,
                              hipStream_t stream)
{
  const float* mu   = (const float*)d_in[0];
  const float* sin_ = (const float*)d_in[1];
  const float* prev = (const float*)d_in[2];
  const float* Sst  = (const float*)d_in[3];
  const float* Uz = (const float*)d_in[4];  const float* uzs = (const float*)d_in[5];
  const float* Wz = (const float*)d_in[6];  const float* wzs = (const float*)d_in[7];
  const float* Ur = (const float*)d_in[8];  const float* urs = (const float*)d_in[9];
  const float* Wr = (const float*)d_in[10]; const float* wrs = (const float*)d_in[11];
  const float* Uh = (const float*)d_in[12]; const float* uhs = (const float*)d_in[13];
  const float* Wh = (const float*)d_in[14]; const float* whs = (const float*)d_in[15];

  char* ws = (char*)d_ws;
  size_t off = 0;
  auto take = [&](size_t bytes) -> char* {
    char* p = ws + off;
    off = (off + bytes + 255) & ~(size_t)255;
    return p;
  };
  unsigned short* Tcm = (unsigned short*)take((size_t)B_ * 2048 * 1024 * 2); // 64 MB
  unsigned short* Sz  = (unsigned short*)take((size_t)B_ * NN_ * 2);        // 32 MB
  unsigned short* Sg  = (unsigned short*)take((size_t)B_ * NN_ * 2);        // 32 MB
  unsigned short* AT  = (unsigned short*)take((size_t)3 * N_ * 2048 * 2);   // 12 MB
  float* sp   = (float*)take(6 * N_ * 4);
  float* z    = (float*)take(B_ * N_ * 4);
  float* gz   = (float*)take(B_ * N_ * 4);
  float* rr   = (float*)take(B_ * N_ * 4);
  float* gr   = (float*)take(B_ * N_ * 4);
  float* h    = (float*)take(B_ * N_ * 4);
  float* gh   = (float*)take(B_ * N_ * 4);
  float* sr   = (float*)take(B_ * N_ * 4);
  float* dA   = (float*)take(64);
  float* dBzr = (float*)take(64);
  float* dBh  = (float*)take(64);
  float* csr  = (float*)take(64);
  if (off > ws_size) return;  // workspace too small (needs ~141 MB)

  float* mu_out = (float*)d_out;
  float* SigOut = (float*)d_out + (size_t)B_ * N_;
  // bf16 copies of the two big f32 inputs live in SigOut's dead region
  // (fully overwritten by the h-gate stage-2 + combine at the end).
  unsigned short* SinH = (unsigned short*)SigOut;                 // 32 MB
  unsigned short* SstH = (unsigned short*)SigOut + (size_t)B_ * NN_; // 32 MB

  const unsigned short* ATz = AT;
  const unsigned short* ATr = AT + (size_t)N_ * 2048;
  const unsigned short* ATh = AT + (size_t)2 * N_ * 2048;

  // ---- prep ----
  conv_bf16<<<2048, 256, 0, stream>>>(sin_, SinH, B_ * NN_ / 4);
  conv_bf16<<<2048, 256, 0, stream>>>(Sst,  SstH, B_ * NN_ / 4);
  softplus6<<<6, 256, 0, stream>>>(uzs, wzs, urs, wrs, uhs, whs, sp);
  scalars1<<<16, 256, 0, stream>>>(mu, prev, sin_, Sst, dA, dBzr);
  build_AT<<<dim3(32, 64, 3), 256, 0, stream>>>(Uz, Wz, Ur, Wr, Uh, Wh, AT);
  gate_gemm<0><<<16, 256, 0, stream>>>(mu, prev, Uz, Wz, z, gz);
  gate_gemm<0><<<16, 256, 0, stream>>>(mu, prev, Ur, Wr, rr, gr);
  sr_csr<<<16, 256, 0, stream>>>(prev, rr, sr, csr);
  gate_gemm<1><<<16, 256, 0, stream>>>(mu, sr, Uh, Wh, h, gh);

  const dim3 gg(8, 8, 16);
  const long tS = (long)2048 * 1024;

  // ---- z gate ----
  gemm_bt<0><<<gg, 256, 0, stream>>>(ATz, 2048, 0, 0,    SinH, 1024, (long)NN_, 1024,
                                     Tcm, 2048, tS, 0,    nullptr, nullptr, nullptr, nullptr, nullptr);
  gemm_bt<0><<<gg, 256, 0, stream>>>(ATz, 2048, 0, 1024, SstH, 1024, (long)NN_, 1024,
                                     Tcm, 2048, tS, 1024, nullptr, nullptr, nullptr, nullptr, nullptr);
  gemm_bt<1><<<gg, 256, 0, stream>>>(ATz, 2048, 0, 0,    Tcm, 2048, tS, 2048,
                                     Sz, 1024, (long)NN_, 0, gz, sp + 0, sp + 1024, dA, dBzr);
  // ---- r gate ----
  gemm_bt<0><<<gg, 256, 0, stream>>>(ATr, 2048, 0, 0,    SinH, 1024, (long)NN_, 1024,
                                     Tcm, 2048, tS, 0,    nullptr, nullptr, nullptr, nullptr, nullptr);
  gemm_bt<0><<<gg, 256, 0, stream>>>(ATr, 2048, 0, 1024, SstH, 1024, (long)NN_, 1024,
                                     Tcm, 2048, tS, 1024, nullptr, nullptr, nullptr, nullptr, nullptr);
  gemm_bt<1><<<gg, 256, 0, stream>>>(ATr, 2048, 0, 0,    Tcm, 2048, tS, 2048,
                                     Sg, 1024, (long)NN_, 0, gr, sp + 2048, sp + 3072, dA, dBzr);
  // ---- sigma_g (in place over Sg) ----
  hadamard_sg<<<16384, 256, 0, stream>>>(Sst, Sg, prev, rr);
  scalars2<<<16, 256, 0, stream>>>(Sg, csr, dBh);
  // ---- h gate ----
  gemm_bt<0><<<gg, 256, 0, stream>>>(ATh, 2048, 0, 0,    SinH, 1024, (long)NN_, 1024,
                                     Tcm, 2048, tS, 0,    nullptr, nullptr, nullptr, nullptr, nullptr);
  gemm_bt<0><<<gg, 256, 0, stream>>>(ATh, 2048, 0, 1024, Sg,   1024, (long)NN_, 1024,
                                     Tcm, 2048, tS, 1024, nullptr, nullptr, nullptr, nullptr, nullptr);
  gemm_bt<2><<<gg, 256, 0, stream>>>(ATh, 2048, 0, 0,    Tcm, 2048, tS, 2048,
                                     SigOut, 1024, (long)NN_, 0, gh, sp + 4096, sp + 5120, dA, dBh);
  // ---- combine ----
  mu_kernel<<<64, 256, 0, stream>>>(z, prev, h, mu_out);
  combine<<<16384, 256, 0, stream>>>(Sz, Sst, z, prev, h, SigOut);
}

// Round 3
// 894.291 us; speedup vs baseline: 1.5900x; 1.4257x over previous
//
#include <hip/hip_runtime.h>
#include <math.h>

// ---------------------------------------------------------------------------
// densityPropGRUCell: B=16, IN=U=1024.
// All heavy GEMMs all-bf16 with global_load_lds (m97 structure).
// Stage 1 per gate computes Tcm[v][i] = sum_j AT[v][j] * S[i][j]  (coalesced)
// Stage 2 computes Sigma[u][v] = sum_k AT[u][k] * Tcm[v][k] + diag, scaled.
// Gate GEMVs: split-K partials (gate_pre*) + activation reduce (gate_act*).
// Workspace (~142 MB): Tcm 64 | Sz 32 | Sg 32 | AT 12 | Ppart 1 | vectors.
// SinH/SstH (bf16 copies of sigma_inputs / Sigma_state) live in d_out's
// SigOut region, which is only written by the h-gate stage-2 at the end.
// ---------------------------------------------------------------------------

#define B_  16
#define N_  1024
#define NN_ (1024*1024)

typedef __bf16 bf16x8 __attribute__((ext_vector_type(8)));
typedef float  f32x4  __attribute__((ext_vector_type(4)));

__device__ __forceinline__ unsigned short f2bf(float f) {
  union { float f; unsigned int u; } v; v.f = f;
  unsigned int r = v.u + 0x7fffu + ((v.u >> 16) & 1u);   // RNE
  return (unsigned short)(r >> 16);
}
__device__ __forceinline__ float bf2f(unsigned short h) {
  union { unsigned int u; float f; } v; v.u = ((unsigned int)h) << 16;
  return v.f;
}
__device__ __forceinline__ float f4get(const float4& v, int q) {
  return q == 0 ? v.x : (q == 1 ? v.y : (q == 2 ? v.z : v.w));
}
__device__ __forceinline__ unsigned short u4get(const ushort4& v, int q) {
  return q == 0 ? v.x : (q == 1 ? v.y : (q == 2 ? v.z : v.w));
}

__device__ __forceinline__ void gload_lds16(const void* g, void* l) {
  __builtin_amdgcn_global_load_lds((__attribute__((address_space(1))) void*)g,
                                   (__attribute__((address_space(3))) void*)l,
                                   16, 0, 0);
}

// ---------------------------------------------------------------------------
// 128x128-tile bf16 MFMA GEMM, BK=32, 4 waves (each 64x64 via 4x4 16x16x32).
//   D[m][n] = sum_k A[m][koffA + k] * B[n][k]
// ---------------------------------------------------------------------------
template<int OMODE>
__global__ __launch_bounds__(256)
void gemm_bt(const unsigned short* __restrict__ A, int lda, long aStride, int koffA,
             const unsigned short* __restrict__ Bm, int ldb, long bStride,
             int K,
             void* __restrict__ Out, int ldo, long oStride, int noff,
             const float* __restrict__ act,
             const float* __restrict__ spU, const float* __restrict__ spW,
             const float* __restrict__ dU, const float* __restrict__ dW)
{
  __shared__ unsigned short Alds[4096];   // [128 rows][32 k] linear
  __shared__ unsigned short Blds[4096];
  const int b = blockIdx.z;
  const int mbase = blockIdx.x * 128, nbase = blockIdx.y * 128;
  const int t = threadIdx.x, lane = t & 63, w = t >> 6;
  const int wm = w >> 1, wc = w & 1;

  f32x4 acc[4][4];
  const f32x4 zero4 = {0.f, 0.f, 0.f, 0.f};
#pragma unroll
  for (int i = 0; i < 4; i++)
#pragma unroll
    for (int j = 0; j < 4; j++) acc[i][j] = zero4;

  const int srow = (w << 4) + (lane >> 2);      // wave-local 16-row panel
  const int scol = (lane & 3) << 3;             // 4 lanes x 8 bf16
  const unsigned short* Ag = A + (size_t)b * aStride + (size_t)(mbase + srow) * lda + koffA + scol;
  const unsigned short* Bg = Bm + (size_t)b * bStride + (size_t)(nbase + srow) * ldb + scol;
  unsigned short* As0 = Alds + (w << 9);        // wave-uniform LDS bases
  unsigned short* As1 = Alds + 2048 + (w << 9);
  unsigned short* Bs0 = Blds + (w << 9);
  unsigned short* Bs1 = Blds + 2048 + (w << 9);
  const size_t a64 = (size_t)64 * lda, b64 = (size_t)64 * ldb;

  for (int k0 = 0; k0 < K; k0 += 32) {
    gload_lds16(Ag + k0,       As0);
    gload_lds16(Ag + k0 + a64, As1);
    gload_lds16(Bg + k0,       Bs0);
    gload_lds16(Bg + k0 + b64, Bs1);
    __syncthreads();
    const int lrow = lane & 15;
    const int lko  = (lane >> 4) << 3;
    bf16x8 av[4], bv[4];
#pragma unroll
    for (int mi = 0; mi < 4; mi++)
      av[mi] = *(const bf16x8*)&Alds[(wm * 64 + mi * 16 + lrow) * 32 + lko];
#pragma unroll
    for (int ni = 0; ni < 4; ni++)
      bv[ni] = *(const bf16x8*)&Blds[(wc * 64 + ni * 16 + lrow) * 32 + lko];
#pragma unroll
    for (int mi = 0; mi < 4; mi++)
#pragma unroll
      for (int ni = 0; ni < 4; ni++)
        acc[mi][ni] = __builtin_amdgcn_mfma_f32_16x16x32_bf16(av[mi], bv[ni], acc[mi][ni], 0, 0, 0);
    __syncthreads();
  }

  if (OMODE == 0) {
    unsigned short* O = (unsigned short*)Out + (size_t)b * oStride + noff;
#pragma unroll
    for (int mi = 0; mi < 4; mi++) {
      const int row0 = mbase + wm * 64 + mi * 16 + ((lane >> 4) << 2);
#pragma unroll
      for (int ni = 0; ni < 4; ni++) {
        const int col = nbase + wc * 64 + ni * 16 + (lane & 15);
#pragma unroll
        for (int r = 0; r < 4; r++)
          O[(size_t)(row0 + r) * ldo + col] = f2bf(acc[mi][ni][r]);
      }
    }
  } else {
    const float* actb = act + b * N_;
    const float dUb = dU[b], dWb = dW[b];
#pragma unroll
    for (int mi = 0; mi < 4; mi++) {
      const int row0 = mbase + wm * 64 + mi * 16 + ((lane >> 4) << 2);
#pragma unroll
      for (int ni = 0; ni < 4; ni++) {
        const int v = nbase + wc * 64 + ni * 16 + (lane & 15);
        const float av = actb[v];
#pragma unroll
        for (int r = 0; r < 4; r++) {
          const int u = row0 + r;
          float val = acc[mi][ni][r];
          if (u == v) val += dUb * spU[u] + dWb * spW[u];
          val *= actb[u] * av;
          if (OMODE == 1)
            ((unsigned short*)Out)[(size_t)b * oStride + (size_t)u * ldo + v] = f2bf(val);
          else
            ((float*)Out)[(size_t)b * oStride + (size_t)u * ldo + v] = val;
        }
      }
    }
  }
}

// --------------------------- small kernels ---------------------------------

__global__ void conv_bf16(const float* __restrict__ in, unsigned short* __restrict__ out, int n4)
{
  int i = blockIdx.x * 256 + threadIdx.x;
  const int stride = gridDim.x * 256;
  for (; i < n4; i += stride) {
    const float4 v = ((const float4*)in)[i];
    ushort4 o;
    o.x = f2bf(v.x); o.y = f2bf(v.y); o.z = f2bf(v.z); o.w = f2bf(v.w);
    ((ushort4*)out)[i] = o;
  }
}

// AT_g[u][k] = (k<1024 ? U_g[k][u] : W_g[k-1024][u]) as bf16. grid(32,64,3).
__global__ void build_AT(const float* __restrict__ Uz, const float* __restrict__ Wz,
                         const float* __restrict__ Ur, const float* __restrict__ Wr,
                         const float* __restrict__ Uh, const float* __restrict__ Wh,
                         unsigned short* __restrict__ AT)
{
  __shared__ float tile[32][33];
  const int g = blockIdx.z;
  const float* U = g == 0 ? Uz : (g == 1 ? Ur : Uh);
  const float* W = g == 0 ? Wz : (g == 1 ? Wr : Wh);
  const int u0  = blockIdx.x * 32;
  const int k0g = blockIdx.y * 32;
  const float* src = (k0g >= 1024) ? W : U;
  const int kloc = k0g & 1023;
  const int tx = threadIdx.x & 31, ty = threadIdx.x >> 5;
  unsigned short* out = AT + (size_t)g * N_ * 2048;
#pragma unroll
  for (int i = 0; i < 32; i += 8) tile[ty + i][tx] = src[(size_t)(kloc + ty + i) * N_ + u0 + tx];
  __syncthreads();
#pragma unroll
  for (int i = 0; i < 32; i += 8)
    out[(size_t)(u0 + ty + i) * 2048 + k0g + tx] = f2bf(tile[tx][ty + i]);
}

__global__ void softplus6(const float* a0, const float* a1, const float* a2,
                          const float* a3, const float* a4, const float* a5,
                          float* __restrict__ sp)
{
  const float* src[6] = {a0, a1, a2, a3, a4, a5};
  const int g = blockIdx.x;
  const float* s = src[g];
  for (int i = threadIdx.x; i < N_; i += 256) {
    float x = s[i];
    sp[g * N_ + i] = (x > 20.f) ? x : log1pf(expf(x));
  }
}

__global__ void scalars1(const float* __restrict__ mu, const float* __restrict__ prev,
                         const float* __restrict__ sin_, const float* __restrict__ Sst,
                         float* __restrict__ dA, float* __restrict__ dBzr)
{
  __shared__ float red[256];
  const int b = blockIdx.x;
  float s1 = 0.f, s2 = 0.f;
  for (int i = threadIdx.x; i < N_; i += 256) {
    const float m = mu[b * N_ + i];
    s1 += m * m + sin_[(size_t)b * NN_ + (size_t)i * (N_ + 1)];
    const float p = prev[b * N_ + i];
    s2 += p * p + Sst[(size_t)b * NN_ + (size_t)i * (N_ + 1)];
  }
  red[threadIdx.x] = s1; __syncthreads();
  for (int s = 128; s > 0; s >>= 1) { if (threadIdx.x < s) red[threadIdx.x] += red[threadIdx.x + s]; __syncthreads(); }
  if (threadIdx.x == 0) dA[b] = red[0];
  __syncthreads();
  red[threadIdx.x] = s2; __syncthreads();
  for (int s = 128; s > 0; s >>= 1) { if (threadIdx.x < s) red[threadIdx.x] += red[threadIdx.x + s]; __syncthreads(); }
  if (threadIdx.x == 0) dBzr[b] = red[0];
}

// ---- gate pre-activations, split-K partials (deterministic, no atomics) ----
// Ppart[g][ks][b][col] ; ks 0..7 covers concat-K 2048 in chunks of 256.
__global__ __launch_bounds__(256)
void gate_pre2(const float* __restrict__ x1, const float* __restrict__ x2,
               const float* __restrict__ U0, const float* __restrict__ W0,
               const float* __restrict__ U1, const float* __restrict__ W1,
               float* __restrict__ Ppart)
{
  const int g  = blockIdx.z;
  const int ks = blockIdx.y;
  const int out = blockIdx.x * 256 + threadIdx.x;   // b*1024+col, b uniform/block
  const int b = out >> 10, col = out & 1023;
  const float* x = (ks < 4) ? x1 : x2;
  const float* Wm = (g == 0) ? ((ks < 4) ? U0 : W0) : ((ks < 4) ? U1 : W1);
  const int k0 = (ks & 3) * 256;
  const float* xb = x + b * N_ + k0;
  const float* wp = Wm + (size_t)k0 * N_ + col;
  float acc = 0.f;
#pragma unroll 8
  for (int k = 0; k < 256; k++)
    acc += xb[k] * wp[(size_t)k * N_];
  Ppart[(g * 8 + ks) * (B_ * N_) + out] = acc;
}

__global__ void gate_act2(const float* __restrict__ P,
                          float* __restrict__ z, float* __restrict__ gz,
                          float* __restrict__ r, float* __restrict__ gr)
{
  const int out = blockIdx.x * 256 + threadIdx.x;
  float a0 = 0.f, a1 = 0.f;
#pragma unroll
  for (int ks = 0; ks < 8; ks++) {
    a0 += P[ks * (B_ * N_) + out];
    a1 += P[(8 + ks) * (B_ * N_) + out];
  }
  const float s0 = 1.f / (1.f + expf(-a0));
  const float s1 = 1.f / (1.f + expf(-a1));
  z[out] = s0; gz[out] = s0 * (1.f - s0);
  r[out] = s1; gr[out] = s1 * (1.f - s1);
}

__global__ __launch_bounds__(256)
void gate_pre1(const float* __restrict__ x1, const float* __restrict__ x2,
               const float* __restrict__ U0, const float* __restrict__ W0,
               float* __restrict__ Ppart)
{
  const int ks = blockIdx.y;
  const int out = blockIdx.x * 256 + threadIdx.x;
  const int b = out >> 10, col = out & 1023;
  const float* x = (ks < 4) ? x1 : x2;
  const float* Wm = (ks < 4) ? U0 : W0;
  const int k0 = (ks & 3) * 256;
  const float* xb = x + b * N_ + k0;
  const float* wp = Wm + (size_t)k0 * N_ + col;
  float acc = 0.f;
#pragma unroll 8
  for (int k = 0; k < 256; k++)
    acc += xb[k] * wp[(size_t)k * N_];
  Ppart[ks * (B_ * N_) + out] = acc;
}

__global__ void gate_act1(const float* __restrict__ P,
                          float* __restrict__ h, float* __restrict__ gh)
{
  const int out = blockIdx.x * 256 + threadIdx.x;
  float a0 = 0.f;
#pragma unroll
  for (int ks = 0; ks < 8; ks++) a0 += P[ks * (B_ * N_) + out];
  const float s = tanhf(a0);
  h[out] = s; gh[out] = 1.f - s * s;
}

__global__ void sr_csr(const float* __restrict__ prev, const float* __restrict__ r,
                       float* __restrict__ sr, float* __restrict__ csr)
{
  __shared__ float red[256];
  const int b = blockIdx.x;
  float s = 0.f;
  for (int i = threadIdx.x; i < N_; i += 256) {
    const float v = prev[b * N_ + i] * r[b * N_ + i];
    sr[b * N_ + i] = v;
    s += v * v;
  }
  red[threadIdx.x] = s; __syncthreads();
  for (int k = 128; k > 0; k >>= 1) { if (threadIdx.x < k) red[threadIdx.x] += red[threadIdx.x + k]; __syncthreads(); }
  if (threadIdx.x == 0) csr[b] = red[0];
}

// sigma_g = Sst.*Sr + p_i p_j Sr + r_i r_j Sst   (in place over Sr, bf16)
__global__ void hadamard_sg(const float* __restrict__ Sst, unsigned short* __restrict__ Sg,
                            const float* __restrict__ prev, const float* __restrict__ r)
{
  const size_t idx = ((size_t)blockIdx.x * 256 + threadIdx.x) * 4;
  const int b = (int)(idx >> 20);
  const int rem = (int)(idx & (NN_ - 1));
  const int i = rem >> 10, j0 = rem & 1023;
  const float pi = prev[b * N_ + i], ri = r[b * N_ + i];
  const float4  ss  = *(const float4*)(Sst + (size_t)b * NN_ + rem);
  const ushort4 sr4 = *(const ushort4*)(Sg + (size_t)b * NN_ + rem);
  ushort4 o;
  unsigned short* op = (unsigned short*)&o;
#pragma unroll
  for (int q = 0; q < 4; q++) {
    const float srv = bf2f(u4get(sr4, q));
    const float stv = f4get(ss, q);
    const float pj = prev[b * N_ + j0 + q];
    const float rj = r[b * N_ + j0 + q];
    op[q] = f2bf(stv * srv + pi * pj * srv + ri * rj * stv);
  }
  *(ushort4*)(Sg + (size_t)b * NN_ + rem) = o;
}

__global__ void scalars2(const unsigned short* __restrict__ Sg,
                         const float* __restrict__ csr, float* __restrict__ dBh)
{
  __shared__ float red[256];
  const int b = blockIdx.x;
  float s = 0.f;
  for (int i = threadIdx.x; i < N_; i += 256)
    s += bf2f(Sg[(size_t)b * NN_ + (size_t)i * (N_ + 1)]);
  red[threadIdx.x] = s; __syncthreads();
  for (int k = 128; k > 0; k >>= 1) { if (threadIdx.x < k) red[threadIdx.x] += red[threadIdx.x + k]; __syncthreads(); }
  if (threadIdx.x == 0) dBh[b] = red[0] + csr[b];
}

__global__ void mu_kernel(const float* __restrict__ z, const float* __restrict__ prev,
                          const float* __restrict__ h, float* __restrict__ mu_out)
{
  const int i = blockIdx.x * 256 + threadIdx.x;
  const float zz = z[i];
  mu_out[i] = zz * prev[i] + (1.f - zz) * h[i];
}

// Sigma_out = a + b - ab - abT, in place over SigOut (which holds Sigma_h).
__global__ void combine(const unsigned short* __restrict__ Sz, const float* __restrict__ Sst,
                        const float* __restrict__ z, const float* __restrict__ prev,
                        const float* __restrict__ h, float* __restrict__ SigOut)
{
  const int row = blockIdx.x;                 // 0..16383 = (b,u)
  const int b = row >> 10, u = row & 1023;
  const float zu = z[b * N_ + u], pu = prev[b * N_ + u], hu = h[b * N_ + u];
  const size_t base = (size_t)b * NN_ + (size_t)u * N_;
  const int j0 = threadIdx.x * 4;
  const ushort4 s4 = *(const ushort4*)(Sz + base + j0);
  const float4 sh = *(const float4*)(SigOut + base + j0);
  const float4 st = *(const float4*)(Sst + base + j0);
  const float4 zv = *(const float4*)(z + b * N_ + j0);
  const float4 pv = *(const float4*)(prev + b * N_ + j0);
  const float4 hv = *(const float4*)(h + b * N_ + j0);
  float o[4];
#pragma unroll
  for (int q = 0; q < 4; q++) {
    const int v = j0 + q;
    const float sz  = bf2f(u4get(s4, q));
    const float shh = f4get(sh, q);
    const float stt = f4get(st, q);
    const float zvv = f4get(zv, q);
    const float pvv = f4get(pv, q);
    const float hvv = f4get(hv, q);
    float res = sz * stt + zu * zvv * stt + pu * pvv * sz
              + sz * shh + (1.f - zu) * (1.f - zvv) * shh + hu * hvv * sz
              - sz * (pu * hvv) - sz * (hu * pvv);
    if (!isfinite(res)) res = 0.f;
    if (u == v) res = fabsf(res);
    o[q] = res;
  }
  float4 ov; ov.x = o[0]; ov.y = o[1]; ov.z = o[2]; ov.w = o[3];
  *(float4*)(SigOut + base + j0) = ov;
}

// ---------------------------------------------------------------------------

extern "C" void kernel_launch(void* const* d_in, const int* in_sizes, int n_in,
                              void* d_out, int out_size, void* d_ws, size_t ws_size,
                              hipStream_t stream)
{
  const float* mu   = (const float*)d_in[0];
  const float* sin_ = (const float*)d_in[1];
  const float* prev = (const float*)d_in[2];
  const float* Sst  = (const float*)d_in[3];
  const float* Uz = (const float*)d_in[4];  const float* uzs = (const float*)d_in[5];
  const float* Wz = (const float*)d_in[6];  const float* wzs = (const float*)d_in[7];
  const float* Ur = (const float*)d_in[8];  const float* urs = (const float*)d_in[9];
  const float* Wr = (const float*)d_in[10]; const float* wrs = (const float*)d_in[11];
  const float* Uh = (const float*)d_in[12]; const float* uhs = (const float*)d_in[13];
  const float* Wh = (const float*)d_in[14]; const float* whs = (const float*)d_in[15];

  char* ws = (char*)d_ws;
  size_t off = 0;
  auto take = [&](size_t bytes) -> char* {
    char* p = ws + off;
    off = (off + bytes + 255) & ~(size_t)255;
    return p;
  };
  unsigned short* Tcm = (unsigned short*)take((size_t)B_ * 2048 * 1024 * 2); // 64 MB
  unsigned short* Sz  = (unsigned short*)take((size_t)B_ * NN_ * 2);        // 32 MB
  unsigned short* Sg  = (unsigned short*)take((size_t)B_ * NN_ * 2);        // 32 MB
  unsigned short* AT  = (unsigned short*)take((size_t)3 * N_ * 2048 * 2);   // 12 MB
  float* Ppart = (float*)take((size_t)16 * B_ * N_ * 4);                    // 1 MB
  float* sp   = (float*)take(6 * N_ * 4);
  float* z    = (float*)take(B_ * N_ * 4);
  float* gz   = (float*)take(B_ * N_ * 4);
  float* rr   = (float*)take(B_ * N_ * 4);
  float* gr   = (float*)take(B_ * N_ * 4);
  float* h    = (float*)take(B_ * N_ * 4);
  float* gh   = (float*)take(B_ * N_ * 4);
  float* sr   = (float*)take(B_ * N_ * 4);
  float* dA   = (float*)take(64);
  float* dBzr = (float*)take(64);
  float* dBh  = (float*)take(64);
  float* csr  = (float*)take(64);
  if (off > ws_size) return;  // workspace too small (needs ~142 MB)

  float* mu_out = (float*)d_out;
  float* SigOut = (float*)d_out + (size_t)B_ * N_;
  // bf16 copies of the two big f32 inputs live in SigOut's dead region
  // (fully overwritten by the h-gate stage-2 + combine at the end).
  unsigned short* SinH = (unsigned short*)SigOut;                 // 32 MB
  unsigned short* SstH = (unsigned short*)SigOut + (size_t)B_ * NN_; // 32 MB

  const unsigned short* ATz = AT;
  const unsigned short* ATr = AT + (size_t)N_ * 2048;
  const unsigned short* ATh = AT + (size_t)2 * N_ * 2048;

  // ---- prep ----
  conv_bf16<<<2048, 256, 0, stream>>>(sin_, SinH, B_ * NN_ / 4);
  conv_bf16<<<2048, 256, 0, stream>>>(Sst,  SstH, B_ * NN_ / 4);
  softplus6<<<6, 256, 0, stream>>>(uzs, wzs, urs, wrs, uhs, whs, sp);
  scalars1<<<16, 256, 0, stream>>>(mu, prev, sin_, Sst, dA, dBzr);
  build_AT<<<dim3(32, 64, 3), 256, 0, stream>>>(Uz, Wz, Ur, Wr, Uh, Wh, AT);
  gate_pre2<<<dim3(64, 8, 2), 256, 0, stream>>>(mu, prev, Uz, Wz, Ur, Wr, Ppart);
  gate_act2<<<64, 256, 0, stream>>>(Ppart, z, gz, rr, gr);
  sr_csr<<<16, 256, 0, stream>>>(prev, rr, sr, csr);
  gate_pre1<<<dim3(64, 8), 256, 0, stream>>>(mu, sr, Uh, Wh, Ppart);
  gate_act1<<<64, 256, 0, stream>>>(Ppart, h, gh);

  const dim3 gg(8, 8, 16);
  const long tS = (long)2048 * 1024;

  // ---- z gate ----
  gemm_bt<0><<<gg, 256, 0, stream>>>(ATz, 2048, 0, 0,    SinH, 1024, (long)NN_, 1024,
                                     Tcm, 2048, tS, 0,    nullptr, nullptr, nullptr, nullptr, nullptr);
  gemm_bt<0><<<gg, 256, 0, stream>>>(ATz, 2048, 0, 1024, SstH, 1024, (long)NN_, 1024,
                                     Tcm, 2048, tS, 1024, nullptr, nullptr, nullptr, nullptr, nullptr);
  gemm_bt<1><<<gg, 256, 0, stream>>>(ATz, 2048, 0, 0,    Tcm, 2048, tS, 2048,
                                     Sz, 1024, (long)NN_, 0, gz, sp + 0, sp + 1024, dA, dBzr);
  // ---- r gate ----
  gemm_bt<0><<<gg, 256, 0, stream>>>(ATr, 2048, 0, 0,    SinH, 1024, (long)NN_, 1024,
                                     Tcm, 2048, tS, 0,    nullptr, nullptr, nullptr, nullptr, nullptr);
  gemm_bt<0><<<gg, 256, 0, stream>>>(ATr, 2048, 0, 1024, SstH, 1024, (long)NN_, 1024,
                                     Tcm, 2048, tS, 1024, nullptr, nullptr, nullptr, nullptr, nullptr);
  gemm_bt<1><<<gg, 256, 0, stream>>>(ATr, 2048, 0, 0,    Tcm, 2048, tS, 2048,
                                     Sg, 1024, (long)NN_, 0, gr, sp + 2048, sp + 3072, dA, dBzr);
  // ---- sigma_g (in place over Sg) ----
  hadamard_sg<<<16384, 256, 0, stream>>>(Sst, Sg, prev, rr);
  scalars2<<<16, 256, 0, stream>>>(Sg, csr, dBh);
  // ---- h gate ----
  gemm_bt<0><<<gg, 256, 0, stream>>>(ATh, 2048, 0, 0,    SinH, 1024, (long)NN_, 1024,
                                     Tcm, 2048, tS, 0,    nullptr, nullptr, nullptr, nullptr, nullptr);
  gemm_bt<0><<<gg, 256, 0, stream>>>(ATh, 2048, 0, 1024, Sg,   1024, (long)NN_, 1024,
                                     Tcm, 2048, tS, 1024, nullptr, nullptr, nullptr, nullptr, nullptr);
  gemm_bt<2><<<gg, 256, 0, stream>>>(ATh, 2048, 0, 0,    Tcm, 2048, tS, 2048,
                                     SigOut, 1024, (long)NN_, 0, gh, sp + 4096, sp + 5120, dA, dBh);
  // ---- combine ----
  mu_kernel<<<64, 256, 0, stream>>>(z, prev, h, mu_out);
  combine<<<16384, 256, 0, stream>>>(Sz, Sst, z, prev, h, SigOut);
}

// Round 4
// 870.167 us; speedup vs baseline: 1.6341x; 1.0277x over previous
//
#include <hip/hip_runtime.h>
#include <math.h>

// ---------------------------------------------------------------------------
// densityPropGRUCell: B=16, IN=U=1024.
// All heavy GEMMs all-bf16 with global_load_lds (m97 structure).
// Round 4: (1) XCD-locality swap — N-block index on blockIdx.x so the blocks
// sharing a B-panel land on one XCD's L2; (2) vectorized bf16 epilogue via
// wave-private XOR-swizzled LDS transpose (full-row dwordx4 stores).
// ---------------------------------------------------------------------------

#define B_  16
#define N_  1024
#define NN_ (1024*1024)

typedef __bf16 bf16x8 __attribute__((ext_vector_type(8)));
typedef float  f32x4  __attribute__((ext_vector_type(4)));
typedef unsigned short ushort8v __attribute__((ext_vector_type(8)));

__device__ __forceinline__ unsigned short f2bf(float f) {
  union { float f; unsigned int u; } v; v.f = f;
  unsigned int r = v.u + 0x7fffu + ((v.u >> 16) & 1u);   // RNE
  return (unsigned short)(r >> 16);
}
__device__ __forceinline__ float bf2f(unsigned short h) {
  union { unsigned int u; float f; } v; v.u = ((unsigned int)h) << 16;
  return v.f;
}
__device__ __forceinline__ float f4get(const float4& v, int q) {
  return q == 0 ? v.x : (q == 1 ? v.y : (q == 2 ? v.z : v.w));
}
__device__ __forceinline__ unsigned short u4get(const ushort4& v, int q) {
  return q == 0 ? v.x : (q == 1 ? v.y : (q == 2 ? v.z : v.w));
}

__device__ __forceinline__ void gload_lds16(const void* g, void* l) {
  __builtin_amdgcn_global_load_lds((__attribute__((address_space(1))) void*)g,
                                   (__attribute__((address_space(3))) void*)l,
                                   16, 0, 0);
}

// ---------------------------------------------------------------------------
// 128x128-tile bf16 MFMA GEMM, BK=32, 4 waves (each 64x64 via 4x4 16x16x32).
//   D[m][n] = sum_k A[m][koffA + k] * B[n][k]
// N-block on blockIdx.x (XCD = bid%8 => one 128-col slab per XCD).
// OMODE 0: raw bf16, rows m of Out at col noff+n  (via LDS-transposed stores)
// OMODE 1: scaled bf16 epilogue (via LDS-transposed stores)
// OMODE 2: scaled f32 epilogue (scalar stores)
// ---------------------------------------------------------------------------
template<int OMODE>
__global__ __launch_bounds__(256)
void gemm_bt(const unsigned short* __restrict__ A, int lda, long aStride, int koffA,
             const unsigned short* __restrict__ Bm, int ldb, long bStride,
             int K,
             void* __restrict__ Out, int ldo, long oStride, int noff,
             const float* __restrict__ act,
             const float* __restrict__ spU, const float* __restrict__ spW,
             const float* __restrict__ dU, const float* __restrict__ dW)
{
  __shared__ unsigned short Alds[4096];   // [128 rows][32 k] linear
  __shared__ unsigned short Blds[4096];
  __shared__ unsigned short Tst[(OMODE == 2) ? 64 : 16384];  // 4 waves x 64x64 bf16
  const int b = blockIdx.z;
  const int mbase = blockIdx.y * 128;   // swapped: m on y
  const int nbase = blockIdx.x * 128;   // n on x ->同 XCD shares B panel
  const int t = threadIdx.x, lane = t & 63, w = t >> 6;
  const int wm = w >> 1, wc = w & 1;

  f32x4 acc[4][4];
  const f32x4 zero4 = {0.f, 0.f, 0.f, 0.f};
#pragma unroll
  for (int i = 0; i < 4; i++)
#pragma unroll
    for (int j = 0; j < 4; j++) acc[i][j] = zero4;

  const int srow = (w << 4) + (lane >> 2);      // wave-local 16-row panel
  const int scol = (lane & 3) << 3;             // 4 lanes x 8 bf16
  const unsigned short* Ag = A + (size_t)b * aStride + (size_t)(mbase + srow) * lda + koffA + scol;
  const unsigned short* Bg = Bm + (size_t)b * bStride + (size_t)(nbase + srow) * ldb + scol;
  unsigned short* As0 = Alds + (w << 9);        // wave-uniform LDS bases
  unsigned short* As1 = Alds + 2048 + (w << 9);
  unsigned short* Bs0 = Blds + (w << 9);
  unsigned short* Bs1 = Blds + 2048 + (w << 9);
  const size_t a64 = (size_t)64 * lda, b64 = (size_t)64 * ldb;
  const int lrow = lane & 15;
  const int lko  = (lane >> 4) << 3;

  for (int k0 = 0; k0 < K; k0 += 32) {
    gload_lds16(Ag + k0,       As0);
    gload_lds16(Ag + k0 + a64, As1);
    gload_lds16(Bg + k0,       Bs0);
    gload_lds16(Bg + k0 + b64, Bs1);
    __syncthreads();
    bf16x8 av[4], bv[4];
#pragma unroll
    for (int mi = 0; mi < 4; mi++)
      av[mi] = *(const bf16x8*)&Alds[(wm * 64 + mi * 16 + lrow) * 32 + lko];
#pragma unroll
    for (int ni = 0; ni < 4; ni++)
      bv[ni] = *(const bf16x8*)&Blds[(wc * 64 + ni * 16 + lrow) * 32 + lko];
#pragma unroll
    for (int mi = 0; mi < 4; mi++)
#pragma unroll
      for (int ni = 0; ni < 4; ni++)
        acc[mi][ni] = __builtin_amdgcn_mfma_f32_16x16x32_bf16(av[mi], bv[ni], acc[mi][ni], 0, 0, 0);
    __syncthreads();
  }

  if (OMODE == 2) {
    const float* actb = act + b * N_;
    const float dUb = dU[b], dWb = dW[b];
#pragma unroll
    for (int mi = 0; mi < 4; mi++) {
      const int row0 = mbase + wm * 64 + mi * 16 + ((lane >> 4) << 2);
#pragma unroll
      for (int ni = 0; ni < 4; ni++) {
        const int v = nbase + wc * 64 + ni * 16 + (lane & 15);
        const float av = actb[v];
#pragma unroll
        for (int r = 0; r < 4; r++) {
          const int u = row0 + r;
          float val = acc[mi][ni][r];
          if (u == v) val += dUb * spU[u] + dWb * spW[u];
          val *= actb[u] * av;
          ((float*)Out)[(size_t)b * oStride + (size_t)u * ldo + v] = val;
        }
      }
    }
  } else {
    // bf16 output via wave-private LDS transpose (XOR-swizzled, conflict-light)
    unsigned short* tst = &Tst[w * 4096];
    const float* actb = (OMODE == 1) ? (act + b * N_) : nullptr;
    float dUb = 0.f, dWb = 0.f;
    if (OMODE == 1) { dUb = dU[b]; dWb = dW[b]; }
    const int m0 = mbase + wm * 64;
    const int n0 = nbase + wc * 64;
#pragma unroll
    for (int mi = 0; mi < 4; mi++) {
#pragma unroll
      for (int ni = 0; ni < 4; ni++) {
        const int rl0 = mi * 16 + ((lane >> 4) << 2);
        const int cl  = ni * 16 + (lane & 15);
#pragma unroll
        for (int r = 0; r < 4; r++) {
          const int rl = rl0 + r;
          float val = acc[mi][ni][r];
          if (OMODE == 1) {
            const int u = m0 + rl, v = n0 + cl;
            if (u == v) val += dUb * spU[u] + dWb * spW[u];
            val *= actb[u] * actb[v];
          }
          // swizzled: element (rl, cl) at rl*64 + (cl&7) + (((cl>>3)^(rl&7))<<3)
          tst[rl * 64 + (cl & 7) + ((((cl >> 3) ^ (rl & 7))) << 3)] = f2bf(val);
        }
      }
    }
    __syncthreads();   // order LDS writes before cross-lane reads (and all waves)
    unsigned short* orow = (unsigned short*)Out + (size_t)b * oStride
                         + (size_t)(m0 + lane) * ldo + noff + n0;
#pragma unroll
    for (int j = 0; j < 8; j++) {
      const int chunk = (j ^ (lane & 7)) << 3;
      ushort8v vv = *(const ushort8v*)&tst[lane * 64 + chunk];
      *(ushort8v*)&orow[j * 8] = vv;
    }
  }
}

// --------------------------- small kernels ---------------------------------

__global__ void conv_bf16(const float* __restrict__ in, unsigned short* __restrict__ out, int n4)
{
  int i = blockIdx.x * 256 + threadIdx.x;
  const int stride = gridDim.x * 256;
  for (; i < n4; i += stride) {
    const float4 v = ((const float4*)in)[i];
    ushort4 o;
    o.x = f2bf(v.x); o.y = f2bf(v.y); o.z = f2bf(v.z); o.w = f2bf(v.w);
    ((ushort4*)out)[i] = o;
  }
}

// AT_g[u][k] = (k<1024 ? U_g[k][u] : W_g[k-1024][u]) as bf16. grid(32,64,3).
__global__ void build_AT(const float* __restrict__ Uz, const float* __restrict__ Wz,
                         const float* __restrict__ Ur, const float* __restrict__ Wr,
                         const float* __restrict__ Uh, const float* __restrict__ Wh,
                         unsigned short* __restrict__ AT)
{
  __shared__ float tile[32][33];
  const int g = blockIdx.z;
  const float* U = g == 0 ? Uz : (g == 1 ? Ur : Uh);
  const float* W = g == 0 ? Wz : (g == 1 ? Wr : Wh);
  const int u0  = blockIdx.x * 32;
  const int k0g = blockIdx.y * 32;
  const float* src = (k0g >= 1024) ? W : U;
  const int kloc = k0g & 1023;
  const int tx = threadIdx.x & 31, ty = threadIdx.x >> 5;
  unsigned short* out = AT + (size_t)g * N_ * 2048;
#pragma unroll
  for (int i = 0; i < 32; i += 8) tile[ty + i][tx] = src[(size_t)(kloc + ty + i) * N_ + u0 + tx];
  __syncthreads();
#pragma unroll
  for (int i = 0; i < 32; i += 8)
    out[(size_t)(u0 + ty + i) * 2048 + k0g + tx] = f2bf(tile[tx][ty + i]);
}

__global__ void softplus6(const float* a0, const float* a1, const float* a2,
                          const float* a3, const float* a4, const float* a5,
                          float* __restrict__ sp)
{
  const float* src[6] = {a0, a1, a2, a3, a4, a5};
  const int g = blockIdx.x;
  const float* s = src[g];
  for (int i = threadIdx.x; i < N_; i += 256) {
    float x = s[i];
    sp[g * N_ + i] = (x > 20.f) ? x : log1pf(expf(x));
  }
}

__global__ void scalars1(const float* __restrict__ mu, const float* __restrict__ prev,
                         const float* __restrict__ sin_, const float* __restrict__ Sst,
                         float* __restrict__ dA, float* __restrict__ dBzr)
{
  __shared__ float red[256];
  const int b = blockIdx.x;
  float s1 = 0.f, s2 = 0.f;
  for (int i = threadIdx.x; i < N_; i += 256) {
    const float m = mu[b * N_ + i];
    s1 += m * m + sin_[(size_t)b * NN_ + (size_t)i * (N_ + 1)];
    const float p = prev[b * N_ + i];
    s2 += p * p + Sst[(size_t)b * NN_ + (size_t)i * (N_ + 1)];
  }
  red[threadIdx.x] = s1; __syncthreads();
  for (int s = 128; s > 0; s >>= 1) { if (threadIdx.x < s) red[threadIdx.x] += red[threadIdx.x + s]; __syncthreads(); }
  if (threadIdx.x == 0) dA[b] = red[0];
  __syncthreads();
  red[threadIdx.x] = s2; __syncthreads();
  for (int s = 128; s > 0; s >>= 1) { if (threadIdx.x < s) red[threadIdx.x] += red[threadIdx.x + s]; __syncthreads(); }
  if (threadIdx.x == 0) dBzr[b] = red[0];
}

// ---- gate pre-activations, split-K partials (deterministic, no atomics) ----
__global__ __launch_bounds__(256)
void gate_pre2(const float* __restrict__ x1, const float* __restrict__ x2,
               const float* __restrict__ U0, const float* __restrict__ W0,
               const float* __restrict__ U1, const float* __restrict__ W1,
               float* __restrict__ Ppart)
{
  const int g  = blockIdx.z;
  const int ks = blockIdx.y;
  const int out = blockIdx.x * 256 + threadIdx.x;   // b*1024+col, b uniform/block
  const int b = out >> 10, col = out & 1023;
  const float* x = (ks < 4) ? x1 : x2;
  const float* Wm = (g == 0) ? ((ks < 4) ? U0 : W0) : ((ks < 4) ? U1 : W1);
  const int k0 = (ks & 3) * 256;
  const float* xb = x + b * N_ + k0;
  const float* wp = Wm + (size_t)k0 * N_ + col;
  float acc = 0.f;
#pragma unroll 8
  for (int k = 0; k < 256; k++)
    acc += xb[k] * wp[(size_t)k * N_];
  Ppart[(g * 8 + ks) * (B_ * N_) + out] = acc;
}

__global__ void gate_act2(const float* __restrict__ P,
                          float* __restrict__ z, float* __restrict__ gz,
                          float* __restrict__ r, float* __restrict__ gr)
{
  const int out = blockIdx.x * 256 + threadIdx.x;
  float a0 = 0.f, a1 = 0.f;
#pragma unroll
  for (int ks = 0; ks < 8; ks++) {
    a0 += P[ks * (B_ * N_) + out];
    a1 += P[(8 + ks) * (B_ * N_) + out];
  }
  const float s0 = 1.f / (1.f + expf(-a0));
  const float s1 = 1.f / (1.f + expf(-a1));
  z[out] = s0; gz[out] = s0 * (1.f - s0);
  r[out] = s1; gr[out] = s1 * (1.f - s1);
}

__global__ __launch_bounds__(256)
void gate_pre1(const float* __restrict__ x1, const float* __restrict__ x2,
               const float* __restrict__ U0, const float* __restrict__ W0,
               float* __restrict__ Ppart)
{
  const int ks = blockIdx.y;
  const int out = blockIdx.x * 256 + threadIdx.x;
  const int b = out >> 10, col = out & 1023;
  const float* x = (ks < 4) ? x1 : x2;
  const float* Wm = (ks < 4) ? U0 : W0;
  const int k0 = (ks & 3) * 256;
  const float* xb = x + b * N_ + k0;
  const float* wp = Wm + (size_t)k0 * N_ + col;
  float acc = 0.f;
#pragma unroll 8
  for (int k = 0; k < 256; k++)
    acc += xb[k] * wp[(size_t)k * N_];
  Ppart[ks * (B_ * N_) + out] = acc;
}

__global__ void gate_act1(const float* __restrict__ P,
                          float* __restrict__ h, float* __restrict__ gh)
{
  const int out = blockIdx.x * 256 + threadIdx.x;
  float a0 = 0.f;
#pragma unroll
  for (int ks = 0; ks < 8; ks++) a0 += P[ks * (B_ * N_) + out];
  const float s = tanhf(a0);
  h[out] = s; gh[out] = 1.f - s * s;
}

__global__ void sr_csr(const float* __restrict__ prev, const float* __restrict__ r,
                       float* __restrict__ sr, float* __restrict__ csr)
{
  __shared__ float red[256];
  const int b = blockIdx.x;
  float s = 0.f;
  for (int i = threadIdx.x; i < N_; i += 256) {
    const float v = prev[b * N_ + i] * r[b * N_ + i];
    sr[b * N_ + i] = v;
    s += v * v;
  }
  red[threadIdx.x] = s; __syncthreads();
  for (int k = 128; k > 0; k >>= 1) { if (threadIdx.x < k) red[threadIdx.x] += red[threadIdx.x + k]; __syncthreads(); }
  if (threadIdx.x == 0) csr[b] = red[0];
}

// sigma_g = Sst.*Sr + p_i p_j Sr + r_i r_j Sst   (in place over Sr, bf16)
__global__ void hadamard_sg(const float* __restrict__ Sst, unsigned short* __restrict__ Sg,
                            const float* __restrict__ prev, const float* __restrict__ r)
{
  const size_t idx = ((size_t)blockIdx.x * 256 + threadIdx.x) * 4;
  const int b = (int)(idx >> 20);
  const int rem = (int)(idx & (NN_ - 1));
  const int i = rem >> 10, j0 = rem & 1023;
  const float pi = prev[b * N_ + i], ri = r[b * N_ + i];
  const float4  ss  = *(const float4*)(Sst + (size_t)b * NN_ + rem);
  const ushort4 sr4 = *(const ushort4*)(Sg + (size_t)b * NN_ + rem);
  ushort4 o;
  unsigned short* op = (unsigned short*)&o;
#pragma unroll
  for (int q = 0; q < 4; q++) {
    const float srv = bf2f(u4get(sr4, q));
    const float stv = f4get(ss, q);
    const float pj = prev[b * N_ + j0 + q];
    const float rj = r[b * N_ + j0 + q];
    op[q] = f2bf(stv * srv + pi * pj * srv + ri * rj * stv);
  }
  *(ushort4*)(Sg + (size_t)b * NN_ + rem) = o;
}

__global__ void scalars2(const unsigned short* __restrict__ Sg,
                         const float* __restrict__ csr, float* __restrict__ dBh)
{
  __shared__ float red[256];
  const int b = blockIdx.x;
  float s = 0.f;
  for (int i = threadIdx.x; i < N_; i += 256)
    s += bf2f(Sg[(size_t)b * NN_ + (size_t)i * (N_ + 1)]);
  red[threadIdx.x] = s; __syncthreads();
  for (int k = 128; k > 0; k >>= 1) { if (threadIdx.x < k) red[threadIdx.x] += red[threadIdx.x + k]; __syncthreads(); }
  if (threadIdx.x == 0) dBh[b] = red[0] + csr[b];
}

__global__ void mu_kernel(const float* __restrict__ z, const float* __restrict__ prev,
                          const float* __restrict__ h, float* __restrict__ mu_out)
{
  const int i = blockIdx.x * 256 + threadIdx.x;
  const float zz = z[i];
  mu_out[i] = zz * prev[i] + (1.f - zz) * h[i];
}

// Sigma_out = a + b - ab - abT, in place over SigOut (which holds Sigma_h).
__global__ void combine(const unsigned short* __restrict__ Sz, const float* __restrict__ Sst,
                        const float* __restrict__ z, const float* __restrict__ prev,
                        const float* __restrict__ h, float* __restrict__ SigOut)
{
  const int row = blockIdx.x;                 // 0..16383 = (b,u)
  const int b = row >> 10, u = row & 1023;
  const float zu = z[b * N_ + u], pu = prev[b * N_ + u], hu = h[b * N_ + u];
  const size_t base = (size_t)b * NN_ + (size_t)u * N_;
  const int j0 = threadIdx.x * 4;
  const ushort4 s4 = *(const ushort4*)(Sz + base + j0);
  const float4 sh = *(const float4*)(SigOut + base + j0);
  const float4 st = *(const float4*)(Sst + base + j0);
  const float4 zv = *(const float4*)(z + b * N_ + j0);
  const float4 pv = *(const float4*)(prev + b * N_ + j0);
  const float4 hv = *(const float4*)(h + b * N_ + j0);
  float o[4];
#pragma unroll
  for (int q = 0; q < 4; q++) {
    const int v = j0 + q;
    const float sz  = bf2f(u4get(s4, q));
    const float shh = f4get(sh, q);
    const float stt = f4get(st, q);
    const float zvv = f4get(zv, q);
    const float pvv = f4get(pv, q);
    const float hvv = f4get(hv, q);
    float res = sz * stt + zu * zvv * stt + pu * pvv * sz
              + sz * shh + (1.f - zu) * (1.f - zvv) * shh + hu * hvv * sz
              - sz * (pu * hvv) - sz * (hu * pvv);
    if (!isfinite(res)) res = 0.f;
    if (u == v) res = fabsf(res);
    o[q] = res;
  }
  float4 ov; ov.x = o[0]; ov.y = o[1]; ov.z = o[2]; ov.w = o[3];
  *(float4*)(SigOut + base + j0) = ov;
}

// ---------------------------------------------------------------------------

extern "C" void kernel_launch(void* const* d_in, const int* in_sizes, int n_in,
                              void* d_out, int out_size, void* d_ws, size_t ws_size,
                              hipStream_t stream)
{
  const float* mu   = (const float*)d_in[0];
  const float* sin_ = (const float*)d_in[1];
  const float* prev = (const float*)d_in[2];
  const float* Sst  = (const float*)d_in[3];
  const float* Uz = (const float*)d_in[4];  const float* uzs = (const float*)d_in[5];
  const float* Wz = (const float*)d_in[6];  const float* wzs = (const float*)d_in[7];
  const float* Ur = (const float*)d_in[8];  const float* urs = (const float*)d_in[9];
  const float* Wr = (const float*)d_in[10]; const float* wrs = (const float*)d_in[11];
  const float* Uh = (const float*)d_in[12]; const float* uhs = (const float*)d_in[13];
  const float* Wh = (const float*)d_in[14]; const float* whs = (const float*)d_in[15];

  char* ws = (char*)d_ws;
  size_t off = 0;
  auto take = [&](size_t bytes) -> char* {
    char* p = ws + off;
    off = (off + bytes + 255) & ~(size_t)255;
    return p;
  };
  unsigned short* Tcm = (unsigned short*)take((size_t)B_ * 2048 * 1024 * 2); // 64 MB
  unsigned short* Sz  = (unsigned short*)take((size_t)B_ * NN_ * 2);        // 32 MB
  unsigned short* Sg  = (unsigned short*)take((size_t)B_ * NN_ * 2);        // 32 MB
  unsigned short* AT  = (unsigned short*)take((size_t)3 * N_ * 2048 * 2);   // 12 MB
  float* Ppart = (float*)take((size_t)16 * B_ * N_ * 4);                    // 1 MB
  float* sp   = (float*)take(6 * N_ * 4);
  float* z    = (float*)take(B_ * N_ * 4);
  float* gz   = (float*)take(B_ * N_ * 4);
  float* rr   = (float*)take(B_ * N_ * 4);
  float* gr   = (float*)take(B_ * N_ * 4);
  float* h    = (float*)take(B_ * N_ * 4);
  float* gh   = (float*)take(B_ * N_ * 4);
  float* sr   = (float*)take(B_ * N_ * 4);
  float* dA   = (float*)take(64);
  float* dBzr = (float*)take(64);
  float* dBh  = (float*)take(64);
  float* csr  = (float*)take(64);
  if (off > ws_size) return;  // workspace too small (needs ~142 MB)

  float* mu_out = (float*)d_out;
  float* SigOut = (float*)d_out + (size_t)B_ * N_;
  // bf16 copies of the two big f32 inputs live in SigOut's dead region
  // (fully overwritten by the h-gate stage-2 + combine at the end).
  unsigned short* SinH = (unsigned short*)SigOut;                 // 32 MB
  unsigned short* SstH = (unsigned short*)SigOut + (size_t)B_ * NN_; // 32 MB

  const unsigned short* ATz = AT;
  const unsigned short* ATr = AT + (size_t)N_ * 2048;
  const unsigned short* ATh = AT + (size_t)2 * N_ * 2048;

  // ---- prep ----
  conv_bf16<<<2048, 256, 0, stream>>>(sin_, SinH, B_ * NN_ / 4);
  conv_bf16<<<2048, 256, 0, stream>>>(Sst,  SstH, B_ * NN_ / 4);
  softplus6<<<6, 256, 0, stream>>>(uzs, wzs, urs, wrs, uhs, whs, sp);
  scalars1<<<16, 256, 0, stream>>>(mu, prev, sin_, Sst, dA, dBzr);
  build_AT<<<dim3(32, 64, 3), 256, 0, stream>>>(Uz, Wz, Ur, Wr, Uh, Wh, AT);
  gate_pre2<<<dim3(64, 8, 2), 256, 0, stream>>>(mu, prev, Uz, Wz, Ur, Wr, Ppart);
  gate_act2<<<64, 256, 0, stream>>>(Ppart, z, gz, rr, gr);
  sr_csr<<<16, 256, 0, stream>>>(prev, rr, sr, csr);
  gate_pre1<<<dim3(64, 8), 256, 0, stream>>>(mu, sr, Uh, Wh, Ppart);
  gate_act1<<<64, 256, 0, stream>>>(Ppart, h, gh);

  const dim3 gg(8, 8, 16);
  const long tS = (long)2048 * 1024;

  // ---- z gate ----
  gemm_bt<0><<<gg, 256, 0, stream>>>(ATz, 2048, 0, 0,    SinH, 1024, (long)NN_, 1024,
                                     Tcm, 2048, tS, 0,    nullptr, nullptr, nullptr, nullptr, nullptr);
  gemm_bt<0><<<gg, 256, 0, stream>>>(ATz, 2048, 0, 1024, SstH, 1024, (long)NN_, 1024,
                                     Tcm, 2048, tS, 1024, nullptr, nullptr, nullptr, nullptr, nullptr);
  gemm_bt<1><<<gg, 256, 0, stream>>>(ATz, 2048, 0, 0,    Tcm, 2048, tS, 2048,
                                     Sz, 1024, (long)NN_, 0, gz, sp + 0, sp + 1024, dA, dBzr);
  // ---- r gate ----
  gemm_bt<0><<<gg, 256, 0, stream>>>(ATr, 2048, 0, 0,    SinH, 1024, (long)NN_, 1024,
                                     Tcm, 2048, tS, 0,    nullptr, nullptr, nullptr, nullptr, nullptr);
  gemm_bt<0><<<gg, 256, 0, stream>>>(ATr, 2048, 0, 1024, SstH, 1024, (long)NN_, 1024,
                                     Tcm, 2048, tS, 1024, nullptr, nullptr, nullptr, nullptr, nullptr);
  gemm_bt<1><<<gg, 256, 0, stream>>>(ATr, 2048, 0, 0,    Tcm, 2048, tS, 2048,
                                     Sg, 1024, (long)NN_, 0, gr, sp + 2048, sp + 3072, dA, dBzr);
  // ---- sigma_g (in place over Sg) ----
  hadamard_sg<<<16384, 256, 0, stream>>>(Sst, Sg, prev, rr);
  scalars2<<<16, 256, 0, stream>>>(Sg, csr, dBh);
  // ---- h gate ----
  gemm_bt<0><<<gg, 256, 0, stream>>>(ATh, 2048, 0, 0,    SinH, 1024, (long)NN_, 1024,
                                     Tcm, 2048, tS, 0,    nullptr, nullptr, nullptr, nullptr, nullptr);
  gemm_bt<0><<<gg, 256, 0, stream>>>(ATh, 2048, 0, 1024, Sg,   1024, (long)NN_, 1024,
                                     Tcm, 2048, tS, 1024, nullptr, nullptr, nullptr, nullptr, nullptr);
  gemm_bt<2><<<gg, 256, 0, stream>>>(ATh, 2048, 0, 0,    Tcm, 2048, tS, 2048,
                                     SigOut, 1024, (long)NN_, 0, gh, sp + 4096, sp + 5120, dA, dBh);
  // ---- combine ----
  mu_kernel<<<64, 256, 0, stream>>>(z, prev, h, mu_out);
  combine<<<16384, 256, 0, stream>>>(Sz, Sst, z, prev, h, SigOut);
}

// Round 5
// 590.633 us; speedup vs baseline: 2.4074x; 1.4733x over previous
//
#include <hip/hip_runtime.h>
#include <math.h>

// ---------------------------------------------------------------------------
// densityPropGRUCell: B=16, IN=U=1024.
// Round 5: 256x256-tile 8-wave GEMM with 4-buffer LDS ring, depth-2 prefetch,
// counted vmcnt(4) across raw s_barrier (T3/T4), and 2-row XOR LDS swizzle
// applied on both sides (pre-swizzled gload source + swizzled ds_read, T2).
// ---------------------------------------------------------------------------

#define B_  16
#define N_  1024
#define NN_ (1024*1024)

typedef __bf16 bf16x8 __attribute__((ext_vector_type(8)));
typedef float  f32x4  __attribute__((ext_vector_type(4)));
typedef unsigned short ushort8v __attribute__((ext_vector_type(8)));

__device__ __forceinline__ unsigned short f2bf(float f) {
  union { float f; unsigned int u; } v; v.f = f;
  unsigned int r = v.u + 0x7fffu + ((v.u >> 16) & 1u);   // RNE
  return (unsigned short)(r >> 16);
}
__device__ __forceinline__ float bf2f(unsigned short h) {
  union { unsigned int u; float f; } v; v.u = ((unsigned int)h) << 16;
  return v.f;
}
__device__ __forceinline__ float f4get(const float4& v, int q) {
  return q == 0 ? v.x : (q == 1 ? v.y : (q == 2 ? v.z : v.w));
}
__device__ __forceinline__ unsigned short u4get(const ushort4& v, int q) {
  return q == 0 ? v.x : (q == 1 ? v.y : (q == 2 ? v.z : v.w));
}

__device__ __forceinline__ void gload_lds16(const void* g, void* l) {
  __builtin_amdgcn_global_load_lds((__attribute__((address_space(1))) void*)g,
                                   (__attribute__((address_space(3))) void*)l,
                                   16, 0, 0);
}

// ---------------------------------------------------------------------------
// 256x256-tile bf16 MFMA GEMM, BK=32, 512 threads = 8 waves (2M x 4N),
// per-wave output 128x64 (8x4 frags of 16x16x32).
//   D[m][n] = sum_k A[m][koffA + k] * B[n][k]
// LDS: ring of 4 buffers x (A 16KB | B 16KB) = 128 KB, prefetch depth 2,
// tile-boundary wait = s_waitcnt vmcnt(4) + raw s_barrier (counted, T4).
// Swizzle: element (row, chunk16B c) of a [.][32k] tile stored at
//   byte sr*128 + (pos ^ (sr&7))*16, sr=row>>1, pos=((row&1)<<2)|c.
// gload source is pre-swizzled so the linear wave-order dest lands right.
// OMODE 0: raw bf16 rows at col noff+n (LDS-transposed 16B stores)
// OMODE 1: scaled bf16 epilogue (LDS-transposed 16B stores)
// OMODE 2: scaled f32 epilogue (scalar stores)
// ---------------------------------------------------------------------------
template<int OMODE>
__global__ __launch_bounds__(512)
void gemm256(const unsigned short* __restrict__ A, int lda, long aStride, int koffA,
             const unsigned short* __restrict__ Bm, int ldb, long bStride,
             int K,
             void* __restrict__ Out, int ldo, long oStride, int noff,
             const float* __restrict__ act,
             const float* __restrict__ spU, const float* __restrict__ spW,
             const float* __restrict__ dU, const float* __restrict__ dW)
{
  __shared__ unsigned short lds[65536];   // 128 KB
  const int b = blockIdx.z;
  const int nbase = blockIdx.x * 256;     // n on x: XCD shares B panel
  const int mbase = blockIdx.y * 256;
  const int t = threadIdx.x, lane = t & 63, w = t >> 6;
  const int wm = w >> 2, wn = w & 3;
  const int NT = K >> 5;

  f32x4 acc[8][4];
  const f32x4 zero4 = {0.f, 0.f, 0.f, 0.f};
#pragma unroll
  for (int i = 0; i < 8; i++)
#pragma unroll
    for (int j = 0; j < 4; j++) acc[i][j] = zero4;

  // ---- staging source addressing (pre-swizzled global, linear LDS dest) ----
  const int l3 = lane >> 3, l7 = lane & 7;
  const int posg = l7 ^ l3;                       // un-swizzled pos for this slot
  const int gr = ((w * 8 + l3) << 1) + (posg >> 2);  // row 0..127 within a half
  const int gc = (posg & 3) << 3;                    // element col within BK=32
  const unsigned short* Ag = A + (size_t)b * aStride + (size_t)(mbase + gr) * lda + koffA + gc;
  const unsigned short* Bg = Bm + (size_t)b * bStride + (size_t)(nbase + gr) * ldb + gc;
  const size_t a128 = (size_t)128 * lda, bb128 = (size_t)128 * ldb;
  char* ldsb = (char*)lds;
  const int wdst = w << 10;                 // wave-uniform dest offset (w*1KB)

  // ---- ds_read per-lane offset within a 1KB (16-row) frag block ----
  const int lrow = lane & 15, c4 = lane >> 4;
  const int aoff = ((lrow >> 1) << 7) + ((((((lrow & 1) << 2) | c4)) ^ (lrow >> 1)) << 4);
  const int abase0 = (wm << 13);            // wm*8192 within A region
  const int bbase0 = 16384 + (wn << 12);    // B region + wn*4096

  auto STAGE = [&](int kt) {
    const int p = kt & 3;
    const size_t ko = (size_t)kt << 5;
    char* base = ldsb + (p << 15);
    gload_lds16(Ag + ko,          base + wdst);
    gload_lds16(Ag + ko + a128,   base + 8192  + wdst);
    gload_lds16(Bg + ko,          base + 16384 + wdst);
    gload_lds16(Bg + ko + bb128,  base + 24576 + wdst);
  };

  STAGE(0); STAGE(1);
  asm volatile("s_waitcnt vmcnt(4)" ::: "memory");
  __builtin_amdgcn_sched_barrier(0);
  __builtin_amdgcn_s_barrier();
  __builtin_amdgcn_sched_barrier(0);

  for (int kt = 0; kt < NT; ++kt) {
    if (kt + 2 < NT) STAGE(kt + 2);
    const char* pbuf = ldsb + ((size_t)(kt & 3) << 15);
    bf16x8 av[8], bv[4];
#pragma unroll
    for (int mi = 0; mi < 8; mi++)
      av[mi] = *(const bf16x8*)(pbuf + abase0 + (mi << 10) + aoff);
#pragma unroll
    for (int ni = 0; ni < 4; ni++)
      bv[ni] = *(const bf16x8*)(pbuf + bbase0 + (ni << 10) + aoff);
#pragma unroll
    for (int ni = 0; ni < 4; ni++)
#pragma unroll
      for (int mi = 0; mi < 8; mi++)
        acc[mi][ni] = __builtin_amdgcn_mfma_f32_16x16x32_bf16(av[mi], bv[ni], acc[mi][ni], 0, 0, 0);
    if (kt + 1 < NT) {
      if (kt + 2 < NT) asm volatile("s_waitcnt vmcnt(4)" ::: "memory");
      else             asm volatile("s_waitcnt vmcnt(0)" ::: "memory");
      __builtin_amdgcn_sched_barrier(0);
      __builtin_amdgcn_s_barrier();
      __builtin_amdgcn_sched_barrier(0);
    }
  }

  if (OMODE == 2) {
    const float* actb = act + b * N_;
    const float dUb = dU[b], dWb = dW[b];
#pragma unroll
    for (int mi = 0; mi < 8; mi++) {
      const int u0 = mbase + wm * 128 + mi * 16 + ((lane >> 4) << 2);
#pragma unroll
      for (int ni = 0; ni < 4; ni++) {
        const int v = nbase + wn * 64 + ni * 16 + (lane & 15);
        const float avv = actb[v];
#pragma unroll
        for (int r = 0; r < 4; r++) {
          const int u = u0 + r;
          float val = acc[mi][ni][r];
          if (u == v) val += dUb * spU[u] + dWb * spW[u];
          val *= actb[u] * avv;
          ((float*)Out)[(size_t)b * oStride + (size_t)u * ldo + v] = val;
        }
      }
    }
  } else {
    __syncthreads();                         // staging fully consumed; reuse ring
    unsigned short* reg = lds + w * 8192;    // per-wave 16KB transpose scratch
    const float* actb = (OMODE == 1) ? (act + b * N_) : nullptr;
    float dUb = 0.f, dWb = 0.f;
    if (OMODE == 1) { dUb = dU[b]; dWb = dW[b]; }
#pragma unroll
    for (int mi = 0; mi < 8; mi++) {
      const int rl0 = mi * 16 + ((lane >> 4) << 2);
#pragma unroll
      for (int ni = 0; ni < 4; ni++) {
        const int cl = ni * 16 + (lane & 15);
#pragma unroll
        for (int r = 0; r < 4; r++) {
          const int rl = rl0 + r;
          float val = acc[mi][ni][r];
          if (OMODE == 1) {
            const int u = mbase + wm * 128 + rl, v = nbase + wn * 64 + cl;
            if (u == v) val += dUb * spU[u] + dWb * spW[u];
            val *= actb[u] * actb[v];
          }
          reg[rl * 64 + cl] = f2bf(val);
        }
      }
    }
    // wave-private region: in-wave lgkm ordering suffices, no barrier
    unsigned short* obase = (unsigned short*)Out + (size_t)b * oStride
        + (size_t)(mbase + wm * 128) * ldo + noff + nbase + wn * 64;
#pragma unroll
    for (int pp = 0; pp < 16; pp++) {
      const int row = pp * 8 + (lane >> 3);
      const int ch = lane & 7;
      ushort8v vv = *(const ushort8v*)&reg[row * 64 + ch * 8];
      *(ushort8v*)(obase + (size_t)row * ldo + ch * 8) = vv;
    }
  }
}

// --------------------------- small kernels ---------------------------------

__global__ void conv_bf16(const float* __restrict__ in, unsigned short* __restrict__ out, int n4)
{
  int i = blockIdx.x * 256 + threadIdx.x;
  const int stride = gridDim.x * 256;
  for (; i < n4; i += stride) {
    const float4 v = ((const float4*)in)[i];
    ushort4 o;
    o.x = f2bf(v.x); o.y = f2bf(v.y); o.z = f2bf(v.z); o.w = f2bf(v.w);
    ((ushort4*)out)[i] = o;
  }
}

// AT_g[u][k] = (k<1024 ? U_g[k][u] : W_g[k-1024][u]) as bf16. grid(32,64,3).
__global__ void build_AT(const float* __restrict__ Uz, const float* __restrict__ Wz,
                         const float* __restrict__ Ur, const float* __restrict__ Wr,
                         const float* __restrict__ Uh, const float* __restrict__ Wh,
                         unsigned short* __restrict__ AT)
{
  __shared__ float tile[32][33];
  const int g = blockIdx.z;
  const float* U = g == 0 ? Uz : (g == 1 ? Ur : Uh);
  const float* W = g == 0 ? Wz : (g == 1 ? Wr : Wh);
  const int u0  = blockIdx.x * 32;
  const int k0g = blockIdx.y * 32;
  const float* src = (k0g >= 1024) ? W : U;
  const int kloc = k0g & 1023;
  const int tx = threadIdx.x & 31, ty = threadIdx.x >> 5;
  unsigned short* out = AT + (size_t)g * N_ * 2048;
#pragma unroll
  for (int i = 0; i < 32; i += 8) tile[ty + i][tx] = src[(size_t)(kloc + ty + i) * N_ + u0 + tx];
  __syncthreads();
#pragma unroll
  for (int i = 0; i < 32; i += 8)
    out[(size_t)(u0 + ty + i) * 2048 + k0g + tx] = f2bf(tile[tx][ty + i]);
}

__global__ void softplus6(const float* a0, const float* a1, const float* a2,
                          const float* a3, const float* a4, const float* a5,
                          float* __restrict__ sp)
{
  const float* src[6] = {a0, a1, a2, a3, a4, a5};
  const int g = blockIdx.x;
  const float* s = src[g];
  for (int i = threadIdx.x; i < N_; i += 256) {
    float x = s[i];
    sp[g * N_ + i] = (x > 20.f) ? x : log1pf(expf(x));
  }
}

__global__ void scalars1(const float* __restrict__ mu, const float* __restrict__ prev,
                         const float* __restrict__ sin_, const float* __restrict__ Sst,
                         float* __restrict__ dA, float* __restrict__ dBzr)
{
  __shared__ float red[256];
  const int b = blockIdx.x;
  float s1 = 0.f, s2 = 0.f;
  for (int i = threadIdx.x; i < N_; i += 256) {
    const float m = mu[b * N_ + i];
    s1 += m * m + sin_[(size_t)b * NN_ + (size_t)i * (N_ + 1)];
    const float p = prev[b * N_ + i];
    s2 += p * p + Sst[(size_t)b * NN_ + (size_t)i * (N_ + 1)];
  }
  red[threadIdx.x] = s1; __syncthreads();
  for (int s = 128; s > 0; s >>= 1) { if (threadIdx.x < s) red[threadIdx.x] += red[threadIdx.x + s]; __syncthreads(); }
  if (threadIdx.x == 0) dA[b] = red[0];
  __syncthreads();
  red[threadIdx.x] = s2; __syncthreads();
  for (int s = 128; s > 0; s >>= 1) { if (threadIdx.x < s) red[threadIdx.x] += red[threadIdx.x + s]; __syncthreads(); }
  if (threadIdx.x == 0) dBzr[b] = red[0];
}

// ---- gate pre-activations, split-K partials (deterministic, no atomics) ----
__global__ __launch_bounds__(256)
void gate_pre2(const float* __restrict__ x1, const float* __restrict__ x2,
               const float* __restrict__ U0, const float* __restrict__ W0,
               const float* __restrict__ U1, const float* __restrict__ W1,
               float* __restrict__ Ppart)
{
  const int g  = blockIdx.z;
  const int ks = blockIdx.y;
  const int out = blockIdx.x * 256 + threadIdx.x;
  const int b = out >> 10, col = out & 1023;
  const float* x = (ks < 4) ? x1 : x2;
  const float* Wm = (g == 0) ? ((ks < 4) ? U0 : W0) : ((ks < 4) ? U1 : W1);
  const int k0 = (ks & 3) * 256;
  const float* xb = x + b * N_ + k0;
  const float* wp = Wm + (size_t)k0 * N_ + col;
  float acc = 0.f;
#pragma unroll 8
  for (int k = 0; k < 256; k++)
    acc += xb[k] * wp[(size_t)k * N_];
  Ppart[(g * 8 + ks) * (B_ * N_) + out] = acc;
}

__global__ void gate_act2(const float* __restrict__ P,
                          float* __restrict__ z, float* __restrict__ gz,
                          float* __restrict__ r, float* __restrict__ gr)
{
  const int out = blockIdx.x * 256 + threadIdx.x;
  float a0 = 0.f, a1 = 0.f;
#pragma unroll
  for (int ks = 0; ks < 8; ks++) {
    a0 += P[ks * (B_ * N_) + out];
    a1 += P[(8 + ks) * (B_ * N_) + out];
  }
  const float s0 = 1.f / (1.f + expf(-a0));
  const float s1 = 1.f / (1.f + expf(-a1));
  z[out] = s0; gz[out] = s0 * (1.f - s0);
  r[out] = s1; gr[out] = s1 * (1.f - s1);
}

__global__ __launch_bounds__(256)
void gate_pre1(const float* __restrict__ x1, const float* __restrict__ x2,
               const float* __restrict__ U0, const float* __restrict__ W0,
               float* __restrict__ Ppart)
{
  const int ks = blockIdx.y;
  const int out = blockIdx.x * 256 + threadIdx.x;
  const int b = out >> 10, col = out & 1023;
  const float* x = (ks < 4) ? x1 : x2;
  const float* Wm = (ks < 4) ? U0 : W0;
  const int k0 = (ks & 3) * 256;
  const float* xb = x + b * N_ + k0;
  const float* wp = Wm + (size_t)k0 * N_ + col;
  float acc = 0.f;
#pragma unroll 8
  for (int k = 0; k < 256; k++)
    acc += xb[k] * wp[(size_t)k * N_];
  Ppart[ks * (B_ * N_) + out] = acc;
}

__global__ void gate_act1(const float* __restrict__ P,
                          float* __restrict__ h, float* __restrict__ gh)
{
  const int out = blockIdx.x * 256 + threadIdx.x;
  float a0 = 0.f;
#pragma unroll
  for (int ks = 0; ks < 8; ks++) a0 += P[ks * (B_ * N_) + out];
  const float s = tanhf(a0);
  h[out] = s; gh[out] = 1.f - s * s;
}

__global__ void sr_csr(const float* __restrict__ prev, const float* __restrict__ r,
                       float* __restrict__ sr, float* __restrict__ csr)
{
  __shared__ float red[256];
  const int b = blockIdx.x;
  float s = 0.f;
  for (int i = threadIdx.x; i < N_; i += 256) {
    const float v = prev[b * N_ + i] * r[b * N_ + i];
    sr[b * N_ + i] = v;
    s += v * v;
  }
  red[threadIdx.x] = s; __syncthreads();
  for (int k = 128; k > 0; k >>= 1) { if (threadIdx.x < k) red[threadIdx.x] += red[threadIdx.x + k]; __syncthreads(); }
  if (threadIdx.x == 0) csr[b] = red[0];
}

// sigma_g = Sst.*Sr + p_i p_j Sr + r_i r_j Sst   (in place over Sr, bf16)
__global__ void hadamard_sg(const float* __restrict__ Sst, unsigned short* __restrict__ Sg,
                            const float* __restrict__ prev, const float* __restrict__ r)
{
  const size_t idx = ((size_t)blockIdx.x * 256 + threadIdx.x) * 4;
  const int b = (int)(idx >> 20);
  const int rem = (int)(idx & (NN_ - 1));
  const int i = rem >> 10, j0 = rem & 1023;
  const float pi = prev[b * N_ + i], ri = r[b * N_ + i];
  const float4  ss  = *(const float4*)(Sst + (size_t)b * NN_ + rem);
  const ushort4 sr4 = *(const ushort4*)(Sg + (size_t)b * NN_ + rem);
  ushort4 o;
  unsigned short* op = (unsigned short*)&o;
#pragma unroll
  for (int q = 0; q < 4; q++) {
    const float srv = bf2f(u4get(sr4, q));
    const float stv = f4get(ss, q);
    const float pj = prev[b * N_ + j0 + q];
    const float rj = r[b * N_ + j0 + q];
    op[q] = f2bf(stv * srv + pi * pj * srv + ri * rj * stv);
  }
  *(ushort4*)(Sg + (size_t)b * NN_ + rem) = o;
}

__global__ void scalars2(const unsigned short* __restrict__ Sg,
                         const float* __restrict__ csr, float* __restrict__ dBh)
{
  __shared__ float red[256];
  const int b = blockIdx.x;
  float s = 0.f;
  for (int i = threadIdx.x; i < N_; i += 256)
    s += bf2f(Sg[(size_t)b * NN_ + (size_t)i * (N_ + 1)]);
  red[threadIdx.x] = s; __syncthreads();
  for (int k = 128; k > 0; k >>= 1) { if (threadIdx.x < k) red[threadIdx.x] += red[threadIdx.x + k]; __syncthreads(); }
  if (threadIdx.x == 0) dBh[b] = red[0] + csr[b];
}

__global__ void mu_kernel(const float* __restrict__ z, const float* __restrict__ prev,
                          const float* __restrict__ h, float* __restrict__ mu_out)
{
  const int i = blockIdx.x * 256 + threadIdx.x;
  const float zz = z[i];
  mu_out[i] = zz * prev[i] + (1.f - zz) * h[i];
}

// Sigma_out = a + b - ab - abT, in place over SigOut (which holds Sigma_h).
__global__ void combine(const unsigned short* __restrict__ Sz, const float* __restrict__ Sst,
                        const float* __restrict__ z, const float* __restrict__ prev,
                        const float* __restrict__ h, float* __restrict__ SigOut)
{
  const int row = blockIdx.x;                 // 0..16383 = (b,u)
  const int b = row >> 10, u = row & 1023;
  const float zu = z[b * N_ + u], pu = prev[b * N_ + u], hu = h[b * N_ + u];
  const size_t base = (size_t)b * NN_ + (size_t)u * N_;
  const int j0 = threadIdx.x * 4;
  const ushort4 s4 = *(const ushort4*)(Sz + base + j0);
  const float4 sh = *(const float4*)(SigOut + base + j0);
  const float4 st = *(const float4*)(Sst + base + j0);
  const float4 zv = *(const float4*)(z + b * N_ + j0);
  const float4 pv = *(const float4*)(prev + b * N_ + j0);
  const float4 hv = *(const float4*)(h + b * N_ + j0);
  float o[4];
#pragma unroll
  for (int q = 0; q < 4; q++) {
    const int v = j0 + q;
    const float sz  = bf2f(u4get(s4, q));
    const float shh = f4get(sh, q);
    const float stt = f4get(st, q);
    const float zvv = f4get(zv, q);
    const float pvv = f4get(pv, q);
    const float hvv = f4get(hv, q);
    float res = sz * stt + zu * zvv * stt + pu * pvv * sz
              + sz * shh + (1.f - zu) * (1.f - zvv) * shh + hu * hvv * sz
              - sz * (pu * hvv) - sz * (hu * pvv);
    if (!isfinite(res)) res = 0.f;
    if (u == v) res = fabsf(res);
    o[q] = res;
  }
  float4 ov; ov.x = o[0]; ov.y = o[1]; ov.z = o[2]; ov.w = o[3];
  *(float4*)(SigOut + base + j0) = ov;
}

// ---------------------------------------------------------------------------

extern "C" void kernel_launch(void* const* d_in, const int* in_sizes, int n_in,
                              void* d_out, int out_size, void* d_ws, size_t ws_size,
                              hipStream_t stream)
{
  const float* mu   = (const float*)d_in[0];
  const float* sin_ = (const float*)d_in[1];
  const float* prev = (const float*)d_in[2];
  const float* Sst  = (const float*)d_in[3];
  const float* Uz = (const float*)d_in[4];  const float* uzs = (const float*)d_in[5];
  const float* Wz = (const float*)d_in[6];  const float* wzs = (const float*)d_in[7];
  const float* Ur = (const float*)d_in[8];  const float* urs = (const float*)d_in[9];
  const float* Wr = (const float*)d_in[10]; const float* wrs = (const float*)d_in[11];
  const float* Uh = (const float*)d_in[12]; const float* uhs = (const float*)d_in[13];
  const float* Wh = (const float*)d_in[14]; const float* whs = (const float*)d_in[15];

  char* ws = (char*)d_ws;
  size_t off = 0;
  auto take = [&](size_t bytes) -> char* {
    char* p = ws + off;
    off = (off + bytes + 255) & ~(size_t)255;
    return p;
  };
  unsigned short* Tcm = (unsigned short*)take((size_t)B_ * 2048 * 1024 * 2); // 64 MB
  unsigned short* Sz  = (unsigned short*)take((size_t)B_ * NN_ * 2);        // 32 MB
  unsigned short* Sg  = (unsigned short*)take((size_t)B_ * NN_ * 2);        // 32 MB
  unsigned short* AT  = (unsigned short*)take((size_t)3 * N_ * 2048 * 2);   // 12 MB
  float* Ppart = (float*)take((size_t)16 * B_ * N_ * 4);                    // 1 MB
  float* sp   = (float*)take(6 * N_ * 4);
  float* z    = (float*)take(B_ * N_ * 4);
  float* gz   = (float*)take(B_ * N_ * 4);
  float* rr   = (float*)take(B_ * N_ * 4);
  float* gr   = (float*)take(B_ * N_ * 4);
  float* h    = (float*)take(B_ * N_ * 4);
  float* gh   = (float*)take(B_ * N_ * 4);
  float* sr   = (float*)take(B_ * N_ * 4);
  float* dA   = (float*)take(64);
  float* dBzr = (float*)take(64);
  float* dBh  = (float*)take(64);
  float* csr  = (float*)take(64);
  if (off > ws_size) return;  // workspace too small (needs ~142 MB)

  float* mu_out = (float*)d_out;
  float* SigOut = (float*)d_out + (size_t)B_ * N_;
  // bf16 copies of the two big f32 inputs live in SigOut's dead region
  // (fully overwritten by the h-gate stage-2 + combine at the end).
  unsigned short* SinH = (unsigned short*)SigOut;                 // 32 MB
  unsigned short* SstH = (unsigned short*)SigOut + (size_t)B_ * NN_; // 32 MB

  const unsigned short* ATz = AT;
  const unsigned short* ATr = AT + (size_t)N_ * 2048;
  const unsigned short* ATh = AT + (size_t)2 * N_ * 2048;

  // ---- prep ----
  conv_bf16<<<2048, 256, 0, stream>>>(sin_, SinH, B_ * NN_ / 4);
  conv_bf16<<<2048, 256, 0, stream>>>(Sst,  SstH, B_ * NN_ / 4);
  softplus6<<<6, 256, 0, stream>>>(uzs, wzs, urs, wrs, uhs, whs, sp);
  scalars1<<<16, 256, 0, stream>>>(mu, prev, sin_, Sst, dA, dBzr);
  build_AT<<<dim3(32, 64, 3), 256, 0, stream>>>(Uz, Wz, Ur, Wr, Uh, Wh, AT);
  gate_pre2<<<dim3(64, 8, 2), 256, 0, stream>>>(mu, prev, Uz, Wz, Ur, Wr, Ppart);
  gate_act2<<<64, 256, 0, stream>>>(Ppart, z, gz, rr, gr);
  sr_csr<<<16, 256, 0, stream>>>(prev, rr, sr, csr);
  gate_pre1<<<dim3(64, 8), 256, 0, stream>>>(mu, sr, Uh, Wh, Ppart);
  gate_act1<<<64, 256, 0, stream>>>(Ppart, h, gh);

  const dim3 gg(4, 4, 16);
  const long tS = (long)2048 * 1024;

  // ---- z gate ----
  gemm256<0><<<gg, 512, 0, stream>>>(ATz, 2048, 0, 0,    SinH, 1024, (long)NN_, 1024,
                                     Tcm, 2048, tS, 0,    nullptr, nullptr, nullptr, nullptr, nullptr);
  gemm256<0><<<gg, 512, 0, stream>>>(ATz, 2048, 0, 1024, SstH, 1024, (long)NN_, 1024,
                                     Tcm, 2048, tS, 1024, nullptr, nullptr, nullptr, nullptr, nullptr);
  gemm256<1><<<gg, 512, 0, stream>>>(ATz, 2048, 0, 0,    Tcm, 2048, tS, 2048,
                                     Sz, 1024, (long)NN_, 0, gz, sp + 0, sp + 1024, dA, dBzr);
  // ---- r gate ----
  gemm256<0><<<gg, 512, 0, stream>>>(ATr, 2048, 0, 0,    SinH, 1024, (long)NN_, 1024,
                                     Tcm, 2048, tS, 0,    nullptr, nullptr, nullptr, nullptr, nullptr);
  gemm256<0><<<gg, 512, 0, stream>>>(ATr, 2048, 0, 1024, SstH, 1024, (long)NN_, 1024,
                                     Tcm, 2048, tS, 1024, nullptr, nullptr, nullptr, nullptr, nullptr);
  gemm256<1><<<gg, 512, 0, stream>>>(ATr, 2048, 0, 0,    Tcm, 2048, tS, 2048,
                                     Sg, 1024, (long)NN_, 0, gr, sp + 2048, sp + 3072, dA, dBzr);
  // ---- sigma_g (in place over Sg) ----
  hadamard_sg<<<16384, 256, 0, stream>>>(Sst, Sg, prev, rr);
  scalars2<<<16, 256, 0, stream>>>(Sg, csr, dBh);
  // ---- h gate ----
  gemm256<0><<<gg, 512, 0, stream>>>(ATh, 2048, 0, 0,    SinH, 1024, (long)NN_, 1024,
                                     Tcm, 2048, tS, 0,    nullptr, nullptr, nullptr, nullptr, nullptr);
  gemm256<0><<<gg, 512, 0, stream>>>(ATh, 2048, 0, 1024, Sg,   1024, (long)NN_, 1024,
                                     Tcm, 2048, tS, 1024, nullptr, nullptr, nullptr, nullptr, nullptr);
  gemm256<2><<<gg, 512, 0, stream>>>(ATh, 2048, 0, 0,    Tcm, 2048, tS, 2048,
                                     SigOut, 1024, (long)NN_, 0, gh, sp + 4096, sp + 5120, dA, dBh);
  // ---- combine ----
  mu_kernel<<<64, 256, 0, stream>>>(z, prev, h, mu_out);
  combine<<<16384, 256, 0, stream>>>(Sz, Sst, z, prev, h, SigOut);
}

// Round 6
// 584.662 us; speedup vs baseline: 2.4320x; 1.0102x over previous
//
#include <hip/hip_runtime.h>
#include <math.h>

// ---------------------------------------------------------------------------
// densityPropGRUCell: B=16, IN=U=1024.
// Round 6: quadrant-pipelined gemm256 — each K-tile's frag ds_reads issue
// under the previous quadrant's MFMAs (register rotation, no extra frags);
// counted vmcnt(4) + 4-buffer ring kept; stage-1 pairs merged per gate.
// ---------------------------------------------------------------------------

#define B_  16
#define N_  1024
#define NN_ (1024*1024)

typedef __bf16 bf16x8 __attribute__((ext_vector_type(8)));
typedef float  f32x4  __attribute__((ext_vector_type(4)));
typedef unsigned short ushort8v __attribute__((ext_vector_type(8)));

__device__ __forceinline__ unsigned short f2bf(float f) {
  union { float f; unsigned int u; } v; v.f = f;
  unsigned int r = v.u + 0x7fffu + ((v.u >> 16) & 1u);   // RNE
  return (unsigned short)(r >> 16);
}
__device__ __forceinline__ float bf2f(unsigned short h) {
  union { unsigned int u; float f; } v; v.u = ((unsigned int)h) << 16;
  return v.f;
}
__device__ __forceinline__ float f4get(const float4& v, int q) {
  return q == 0 ? v.x : (q == 1 ? v.y : (q == 2 ? v.z : v.w));
}
__device__ __forceinline__ unsigned short u4get(const ushort4& v, int q) {
  return q == 0 ? v.x : (q == 1 ? v.y : (q == 2 ? v.z : v.w));
}

__device__ __forceinline__ void gload_lds16(const void* g, void* l) {
  __builtin_amdgcn_global_load_lds((__attribute__((address_space(1))) void*)g,
                                   (__attribute__((address_space(3))) void*)l,
                                   16, 0, 0);
}

// ---------------------------------------------------------------------------
// 256x256-tile bf16 MFMA GEMM, BK=32, 512 threads = 8 waves (2M x 4N),
// per-wave output 128x64.  D[m][n] = sum_k A[m][koffA+k] * B[n][k]
// 4-buffer LDS ring (128KB), depth-2 prefetch, counted vmcnt(4).
// Quadrant pipeline per kt:
//   Q0(a0,b0)+rd b1 | Q1(a0,b1)+rd a1 | STAGE;vmcnt;barrier |
//   Q2(a1,b0)+rd a0' | Q3(a1,b1)+rd b0'     (reads hide under MFMAs)
// PAIR=1: blockIdx.x splits into two halves reading Bm (noff 0) / Bm2
// (noff 1024) — merges the per-gate stage-1 pair into one launch.
// OMODE 0: raw bf16 rows (LDS-transposed 16B stores)
// OMODE 1: scaled bf16 epilogue; OMODE 2: scaled f32 epilogue.
// ---------------------------------------------------------------------------
template<int OMODE, int PAIR>
__global__ __launch_bounds__(512)
void gemm256(const unsigned short* __restrict__ A, int lda, long aStride, int koffA,
             const unsigned short* __restrict__ Bm, const unsigned short* __restrict__ Bm2,
             int ldb, long bStride, int K,
             void* __restrict__ Out, int ldo, long oStride, int noff,
             const float* __restrict__ act,
             const float* __restrict__ spU, const float* __restrict__ spW,
             const float* __restrict__ dU, const float* __restrict__ dW)
{
  __shared__ unsigned short lds[65536];   // 128 KB
  const int b = blockIdx.z;
  const unsigned short* Bsel = Bm;
  int nofx = noff, nbx = blockIdx.x;
  if (PAIR) {
    const int half = gridDim.x >> 1;
    if (nbx >= half) { Bsel = Bm2; nofx = 1024; nbx -= half; }
  }
  const int nbase = nbx * 256;
  const int mbase = blockIdx.y * 256;
  const int t = threadIdx.x, lane = t & 63, w = t >> 6;
  const int wm = w >> 2, wn = w & 3;
  const int NT = K >> 5;

  f32x4 acc[8][4];
  const f32x4 zero4 = {0.f, 0.f, 0.f, 0.f};
#pragma unroll
  for (int i = 0; i < 8; i++)
#pragma unroll
    for (int j = 0; j < 4; j++) acc[i][j] = zero4;

  // ---- staging source addressing (pre-swizzled global, linear LDS dest) ----
  const int l3 = lane >> 3, l7 = lane & 7;
  const int posg = l7 ^ l3;
  const int gr = ((w * 8 + l3) << 1) + (posg >> 2);
  const int gc = (posg & 3) << 3;
  const unsigned short* Ag = A + (size_t)b * aStride + (size_t)(mbase + gr) * lda + koffA + gc;
  const unsigned short* Bg = Bsel + (size_t)b * bStride + (size_t)(nbase + gr) * ldb + gc;
  const size_t a128 = (size_t)128 * lda, bb128 = (size_t)128 * ldb;
  char* ldsb = (char*)lds;
  const int wdst = w << 10;

  // ---- ds_read per-lane offset within a 1KB (16-row) frag block ----
  const int lrow = lane & 15, c4 = lane >> 4;
  const int aoff = ((lrow >> 1) << 7) + ((((((lrow & 1) << 2) | c4)) ^ (lrow >> 1)) << 4);
  const int abase0 = (wm << 13);
  const int bbase0 = 16384 + (wn << 12);

  auto STAGE = [&](int kt) {
    const int p = kt & 3;
    const size_t ko = (size_t)kt << 5;
    char* base = ldsb + (p << 15);
    gload_lds16(Ag + ko,          base + wdst);
    gload_lds16(Ag + ko + a128,   base + 8192  + wdst);
    gload_lds16(Bg + ko,          base + 16384 + wdst);
    gload_lds16(Bg + ko + bb128,  base + 24576 + wdst);
  };
  auto LDA8 = [&](const char* pbuf, int mi) -> bf16x8 {
    return *(const bf16x8*)(pbuf + abase0 + (mi << 10) + aoff);
  };
  auto LDB8 = [&](const char* pbuf, int ni) -> bf16x8 {
    return *(const bf16x8*)(pbuf + bbase0 + (ni << 10) + aoff);
  };

  STAGE(0); STAGE(1);
  asm volatile("s_waitcnt vmcnt(4)" ::: "memory");
  __builtin_amdgcn_sched_barrier(0);
  __builtin_amdgcn_s_barrier();
  __builtin_amdgcn_sched_barrier(0);

  bf16x8 a0[4], a1[4], b0[2], b1[2];
#pragma unroll
  for (int i = 0; i < 4; i++) a0[i] = LDA8(ldsb, i);
#pragma unroll
  for (int i = 0; i < 2; i++) b0[i] = LDB8(ldsb, i);

  for (int kt = 0; kt < NT; ++kt) {
    const char* pbuf = ldsb + ((size_t)(kt & 3) << 15);
    const char* pnxt = ldsb + ((size_t)((kt + 1) & 3) << 15);
    // Q0: (a0,b0) -> acc[0:4][0:2], prefetch b1
#pragma unroll
    for (int i = 0; i < 2; i++) b1[i] = LDB8(pbuf, 2 + i);
#pragma unroll
    for (int ni = 0; ni < 2; ni++)
#pragma unroll
      for (int mi = 0; mi < 4; mi++)
        acc[mi][ni] = __builtin_amdgcn_mfma_f32_16x16x32_bf16(a0[mi], b0[ni], acc[mi][ni], 0, 0, 0);
    // Q1: (a0,b1) -> acc[0:4][2:4], prefetch a1
#pragma unroll
    for (int i = 0; i < 4; i++) a1[i] = LDA8(pbuf, 4 + i);
#pragma unroll
    for (int ni = 0; ni < 2; ni++)
#pragma unroll
      for (int mi = 0; mi < 4; mi++)
        acc[mi][2 + ni] = __builtin_amdgcn_mfma_f32_16x16x32_bf16(a0[mi], b1[ni], acc[mi][2 + ni], 0, 0, 0);
    // boundary: stage kt+2, counted wait for buf kt+1, barrier
    if (kt + 2 < NT) {
      STAGE(kt + 2);
      asm volatile("s_waitcnt vmcnt(4)" ::: "memory");
    } else {
      asm volatile("s_waitcnt vmcnt(0)" ::: "memory");
    }
    __builtin_amdgcn_sched_barrier(0);
    __builtin_amdgcn_s_barrier();
    __builtin_amdgcn_sched_barrier(0);
    // Q2: (a1,b0) -> acc[4:8][0:2], prefetch next a0 from buf kt+1
    if (kt + 1 < NT) {
#pragma unroll
      for (int i = 0; i < 4; i++) a0[i] = LDA8(pnxt, i);
    }
#pragma unroll
    for (int ni = 0; ni < 2; ni++)
#pragma unroll
      for (int mi = 0; mi < 4; mi++)
        acc[4 + mi][ni] = __builtin_amdgcn_mfma_f32_16x16x32_bf16(a1[mi], b0[ni], acc[4 + mi][ni], 0, 0, 0);
    // Q3: (a1,b1) -> acc[4:8][2:4], prefetch next b0
    if (kt + 1 < NT) {
#pragma unroll
      for (int i = 0; i < 2; i++) b0[i] = LDB8(pnxt, i);
    }
#pragma unroll
    for (int ni = 0; ni < 2; ni++)
#pragma unroll
      for (int mi = 0; mi < 4; mi++)
        acc[4 + mi][2 + ni] = __builtin_amdgcn_mfma_f32_16x16x32_bf16(a1[mi], b1[ni], acc[4 + mi][2 + ni], 0, 0, 0);
  }

  if (OMODE == 2) {
    const float* actb = act + b * N_;
    const float dUb = dU[b], dWb = dW[b];
#pragma unroll
    for (int mi = 0; mi < 8; mi++) {
      const int u0 = mbase + wm * 128 + mi * 16 + ((lane >> 4) << 2);
#pragma unroll
      for (int ni = 0; ni < 4; ni++) {
        const int v = nbase + wn * 64 + ni * 16 + (lane & 15);
        const float avv = actb[v];
#pragma unroll
        for (int r = 0; r < 4; r++) {
          const int u = u0 + r;
          float val = acc[mi][ni][r];
          if (u == v) val += dUb * spU[u] + dWb * spW[u];
          val *= actb[u] * avv;
          ((float*)Out)[(size_t)b * oStride + (size_t)u * ldo + v] = val;
        }
      }
    }
  } else {
    __syncthreads();                         // staging fully consumed; reuse ring
    unsigned short* reg = lds + w * 8192;    // per-wave 16KB transpose scratch
    const float* actb = (OMODE == 1) ? (act + b * N_) : nullptr;
    float dUb = 0.f, dWb = 0.f;
    if (OMODE == 1) { dUb = dU[b]; dWb = dW[b]; }
#pragma unroll
    for (int mi = 0; mi < 8; mi++) {
      const int rl0 = mi * 16 + ((lane >> 4) << 2);
#pragma unroll
      for (int ni = 0; ni < 4; ni++) {
        const int cl = ni * 16 + (lane & 15);
#pragma unroll
        for (int r = 0; r < 4; r++) {
          const int rl = rl0 + r;
          float val = acc[mi][ni][r];
          if (OMODE == 1) {
            const int u = mbase + wm * 128 + rl, v = nbase + wn * 64 + cl;
            if (u == v) val += dUb * spU[u] + dWb * spW[u];
            val *= actb[u] * actb[v];
          }
          reg[rl * 64 + cl] = f2bf(val);
        }
      }
    }
    unsigned short* obase = (unsigned short*)Out + (size_t)b * oStride
        + (size_t)(mbase + wm * 128) * ldo + nofx + nbase + wn * 64;
#pragma unroll
    for (int pp = 0; pp < 16; pp++) {
      const int row = pp * 8 + (lane >> 3);
      const int ch = lane & 7;
      ushort8v vv = *(const ushort8v*)&reg[row * 64 + ch * 8];
      *(ushort8v*)(obase + (size_t)row * ldo + ch * 8) = vv;
    }
  }
}

// --------------------------- small kernels ---------------------------------

__global__ void conv_bf16(const float* __restrict__ in, unsigned short* __restrict__ out, int n4)
{
  int i = blockIdx.x * 256 + threadIdx.x;
  const int stride = gridDim.x * 256;
  for (; i < n4; i += stride) {
    const float4 v = ((const float4*)in)[i];
    ushort4 o;
    o.x = f2bf(v.x); o.y = f2bf(v.y); o.z = f2bf(v.z); o.w = f2bf(v.w);
    ((ushort4*)out)[i] = o;
  }
}

// AT_g[u][k] = (k<1024 ? U_g[k][u] : W_g[k-1024][u]) as bf16. grid(32,64,3).
__global__ void build_AT(const float* __restrict__ Uz, const float* __restrict__ Wz,
                         const float* __restrict__ Ur, const float* __restrict__ Wr,
                         const float* __restrict__ Uh, const float* __restrict__ Wh,
                         unsigned short* __restrict__ AT)
{
  __shared__ float tile[32][33];
  const int g = blockIdx.z;
  const float* U = g == 0 ? Uz : (g == 1 ? Ur : Uh);
  const float* W = g == 0 ? Wz : (g == 1 ? Wr : Wh);
  const int u0  = blockIdx.x * 32;
  const int k0g = blockIdx.y * 32;
  const float* src = (k0g >= 1024) ? W : U;
  const int kloc = k0g & 1023;
  const int tx = threadIdx.x & 31, ty = threadIdx.x >> 5;
  unsigned short* out = AT + (size_t)g * N_ * 2048;
#pragma unroll
  for (int i = 0; i < 32; i += 8) tile[ty + i][tx] = src[(size_t)(kloc + ty + i) * N_ + u0 + tx];
  __syncthreads();
#pragma unroll
  for (int i = 0; i < 32; i += 8)
    out[(size_t)(u0 + ty + i) * 2048 + k0g + tx] = f2bf(tile[tx][ty + i]);
}

__global__ void softplus6(const float* a0, const float* a1, const float* a2,
                          const float* a3, const float* a4, const float* a5,
                          float* __restrict__ sp)
{
  const float* src[6] = {a0, a1, a2, a3, a4, a5};
  const int g = blockIdx.x;
  const float* s = src[g];
  for (int i = threadIdx.x; i < N_; i += 256) {
    float x = s[i];
    sp[g * N_ + i] = (x > 20.f) ? x : log1pf(expf(x));
  }
}

__global__ void scalars1(const float* __restrict__ mu, const float* __restrict__ prev,
                         const float* __restrict__ sin_, const float* __restrict__ Sst,
                         float* __restrict__ dA, float* __restrict__ dBzr)
{
  __shared__ float red[256];
  const int b = blockIdx.x;
  float s1 = 0.f, s2 = 0.f;
  for (int i = threadIdx.x; i < N_; i += 256) {
    const float m = mu[b * N_ + i];
    s1 += m * m + sin_[(size_t)b * NN_ + (size_t)i * (N_ + 1)];
    const float p = prev[b * N_ + i];
    s2 += p * p + Sst[(size_t)b * NN_ + (size_t)i * (N_ + 1)];
  }
  red[threadIdx.x] = s1; __syncthreads();
  for (int s = 128; s > 0; s >>= 1) { if (threadIdx.x < s) red[threadIdx.x] += red[threadIdx.x + s]; __syncthreads(); }
  if (threadIdx.x == 0) dA[b] = red[0];
  __syncthreads();
  red[threadIdx.x] = s2; __syncthreads();
  for (int s = 128; s > 0; s >>= 1) { if (threadIdx.x < s) red[threadIdx.x] += red[threadIdx.x + s]; __syncthreads(); }
  if (threadIdx.x == 0) dBzr[b] = red[0];
}

// ---- gate pre-activations, split-K partials (deterministic, no atomics) ----
__global__ __launch_bounds__(256)
void gate_pre2(const float* __restrict__ x1, const float* __restrict__ x2,
               const float* __restrict__ U0, const float* __restrict__ W0,
               const float* __restrict__ U1, const float* __restrict__ W1,
               float* __restrict__ Ppart)
{
  const int g  = blockIdx.z;
  const int ks = blockIdx.y;
  const int out = blockIdx.x * 256 + threadIdx.x;
  const int b = out >> 10, col = out & 1023;
  const float* x = (ks < 4) ? x1 : x2;
  const float* Wm = (g == 0) ? ((ks < 4) ? U0 : W0) : ((ks < 4) ? U1 : W1);
  const int k0 = (ks & 3) * 256;
  const float* xb = x + b * N_ + k0;
  const float* wp = Wm + (size_t)k0 * N_ + col;
  float acc = 0.f;
#pragma unroll 8
  for (int k = 0; k < 256; k++)
    acc += xb[k] * wp[(size_t)k * N_];
  Ppart[(g * 8 + ks) * (B_ * N_) + out] = acc;
}

__global__ void gate_act2(const float* __restrict__ P,
                          float* __restrict__ z, float* __restrict__ gz,
                          float* __restrict__ r, float* __restrict__ gr)
{
  const int out = blockIdx.x * 256 + threadIdx.x;
  float a0 = 0.f, a1 = 0.f;
#pragma unroll
  for (int ks = 0; ks < 8; ks++) {
    a0 += P[ks * (B_ * N_) + out];
    a1 += P[(8 + ks) * (B_ * N_) + out];
  }
  const float s0 = 1.f / (1.f + expf(-a0));
  const float s1 = 1.f / (1.f + expf(-a1));
  z[out] = s0; gz[out] = s0 * (1.f - s0);
  r[out] = s1; gr[out] = s1 * (1.f - s1);
}

__global__ __launch_bounds__(256)
void gate_pre1(const float* __restrict__ x1, const float* __restrict__ x2,
               const float* __restrict__ U0, const float* __restrict__ W0,
               float* __restrict__ Ppart)
{
  const int ks = blockIdx.y;
  const int out = blockIdx.x * 256 + threadIdx.x;
  const int b = out >> 10, col = out & 1023;
  const float* x = (ks < 4) ? x1 : x2;
  const float* Wm = (ks < 4) ? U0 : W0;
  const int k0 = (ks & 3) * 256;
  const float* xb = x + b * N_ + k0;
  const float* wp = Wm + (size_t)k0 * N_ + col;
  float acc = 0.f;
#pragma unroll 8
  for (int k = 0; k < 256; k++)
    acc += xb[k] * wp[(size_t)k * N_];
  Ppart[ks * (B_ * N_) + out] = acc;
}

__global__ void gate_act1(const float* __restrict__ P,
                          float* __restrict__ h, float* __restrict__ gh)
{
  const int out = blockIdx.x * 256 + threadIdx.x;
  float a0 = 0.f;
#pragma unroll
  for (int ks = 0; ks < 8; ks++) a0 += P[ks * (B_ * N_) + out];
  const float s = tanhf(a0);
  h[out] = s; gh[out] = 1.f - s * s;
}

__global__ void sr_csr(const float* __restrict__ prev, const float* __restrict__ r,
                       float* __restrict__ sr, float* __restrict__ csr)
{
  __shared__ float red[256];
  const int b = blockIdx.x;
  float s = 0.f;
  for (int i = threadIdx.x; i < N_; i += 256) {
    const float v = prev[b * N_ + i] * r[b * N_ + i];
    sr[b * N_ + i] = v;
    s += v * v;
  }
  red[threadIdx.x] = s; __syncthreads();
  for (int k = 128; k > 0; k >>= 1) { if (threadIdx.x < k) red[threadIdx.x] += red[threadIdx.x + k]; __syncthreads(); }
  if (threadIdx.x == 0) csr[b] = red[0];
}

// sigma_g = Sst.*Sr + p_i p_j Sr + r_i r_j Sst   (in place over Sr, bf16)
__global__ void hadamard_sg(const float* __restrict__ Sst, unsigned short* __restrict__ Sg,
                            const float* __restrict__ prev, const float* __restrict__ r)
{
  const size_t idx = ((size_t)blockIdx.x * 256 + threadIdx.x) * 4;
  const int b = (int)(idx >> 20);
  const int rem = (int)(idx & (NN_ - 1));
  const int i = rem >> 10, j0 = rem & 1023;
  const float pi = prev[b * N_ + i], ri = r[b * N_ + i];
  const float4  ss  = *(const float4*)(Sst + (size_t)b * NN_ + rem);
  const ushort4 sr4 = *(const ushort4*)(Sg + (size_t)b * NN_ + rem);
  ushort4 o;
  unsigned short* op = (unsigned short*)&o;
#pragma unroll
  for (int q = 0; q < 4; q++) {
    const float srv = bf2f(u4get(sr4, q));
    const float stv = f4get(ss, q);
    const float pj = prev[b * N_ + j0 + q];
    const float rj = r[b * N_ + j0 + q];
    op[q] = f2bf(stv * srv + pi * pj * srv + ri * rj * stv);
  }
  *(ushort4*)(Sg + (size_t)b * NN_ + rem) = o;
}

__global__ void scalars2(const unsigned short* __restrict__ Sg,
                         const float* __restrict__ csr, float* __restrict__ dBh)
{
  __shared__ float red[256];
  const int b = blockIdx.x;
  float s = 0.f;
  for (int i = threadIdx.x; i < N_; i += 256)
    s += bf2f(Sg[(size_t)b * NN_ + (size_t)i * (N_ + 1)]);
  red[threadIdx.x] = s; __syncthreads();
  for (int k = 128; k > 0; k >>= 1) { if (threadIdx.x < k) red[threadIdx.x] += red[threadIdx.x + k]; __syncthreads(); }
  if (threadIdx.x == 0) dBh[b] = red[0] + csr[b];
}

__global__ void mu_kernel(const float* __restrict__ z, const float* __restrict__ prev,
                          const float* __restrict__ h, float* __restrict__ mu_out)
{
  const int i = blockIdx.x * 256 + threadIdx.x;
  const float zz = z[i];
  mu_out[i] = zz * prev[i] + (1.f - zz) * h[i];
}

// Sigma_out = a + b - ab - abT, in place over SigOut (which holds Sigma_h).
__global__ void combine(const unsigned short* __restrict__ Sz, const float* __restrict__ Sst,
                        const float* __restrict__ z, const float* __restrict__ prev,
                        const float* __restrict__ h, float* __restrict__ SigOut)
{
  const int row = blockIdx.x;                 // 0..16383 = (b,u)
  const int b = row >> 10, u = row & 1023;
  const float zu = z[b * N_ + u], pu = prev[b * N_ + u], hu = h[b * N_ + u];
  const size_t base = (size_t)b * NN_ + (size_t)u * N_;
  const int j0 = threadIdx.x * 4;
  const ushort4 s4 = *(const ushort4*)(Sz + base + j0);
  const float4 sh = *(const float4*)(SigOut + base + j0);
  const float4 st = *(const float4*)(Sst + base + j0);
  const float4 zv = *(const float4*)(z + b * N_ + j0);
  const float4 pv = *(const float4*)(prev + b * N_ + j0);
  const float4 hv = *(const float4*)(h + b * N_ + j0);
  float o[4];
#pragma unroll
  for (int q = 0; q < 4; q++) {
    const int v = j0 + q;
    const float sz  = bf2f(u4get(s4, q));
    const float shh = f4get(sh, q);
    const float stt = f4get(st, q);
    const float zvv = f4get(zv, q);
    const float pvv = f4get(pv, q);
    const float hvv = f4get(hv, q);
    float res = sz * stt + zu * zvv * stt + pu * pvv * sz
              + sz * shh + (1.f - zu) * (1.f - zvv) * shh + hu * hvv * sz
              - sz * (pu * hvv) - sz * (hu * pvv);
    if (!isfinite(res)) res = 0.f;
    if (u == v) res = fabsf(res);
    o[q] = res;
  }
  float4 ov; ov.x = o[0]; ov.y = o[1]; ov.z = o[2]; ov.w = o[3];
  *(float4*)(SigOut + base + j0) = ov;
}

// ---------------------------------------------------------------------------

extern "C" void kernel_launch(void* const* d_in, const int* in_sizes, int n_in,
                              void* d_out, int out_size, void* d_ws, size_t ws_size,
                              hipStream_t stream)
{
  const float* mu   = (const float*)d_in[0];
  const float* sin_ = (const float*)d_in[1];
  const float* prev = (const float*)d_in[2];
  const float* Sst  = (const float*)d_in[3];
  const float* Uz = (const float*)d_in[4];  const float* uzs = (const float*)d_in[5];
  const float* Wz = (const float*)d_in[6];  const float* wzs = (const float*)d_in[7];
  const float* Ur = (const float*)d_in[8];  const float* urs = (const float*)d_in[9];
  const float* Wr = (const float*)d_in[10]; const float* wrs = (const float*)d_in[11];
  const float* Uh = (const float*)d_in[12]; const float* uhs = (const float*)d_in[13];
  const float* Wh = (const float*)d_in[14]; const float* whs = (const float*)d_in[15];

  char* ws = (char*)d_ws;
  size_t off = 0;
  auto take = [&](size_t bytes) -> char* {
    char* p = ws + off;
    off = (off + bytes + 255) & ~(size_t)255;
    return p;
  };
  unsigned short* Tcm = (unsigned short*)take((size_t)B_ * 2048 * 1024 * 2); // 64 MB
  unsigned short* Sz  = (unsigned short*)take((size_t)B_ * NN_ * 2);        // 32 MB
  unsigned short* Sg  = (unsigned short*)take((size_t)B_ * NN_ * 2);        // 32 MB
  unsigned short* AT  = (unsigned short*)take((size_t)3 * N_ * 2048 * 2);   // 12 MB
  float* Ppart = (float*)take((size_t)16 * B_ * N_ * 4);                    // 1 MB
  float* sp   = (float*)take(6 * N_ * 4);
  float* z    = (float*)take(B_ * N_ * 4);
  float* gz   = (float*)take(B_ * N_ * 4);
  float* rr   = (float*)take(B_ * N_ * 4);
  float* gr   = (float*)take(B_ * N_ * 4);
  float* h    = (float*)take(B_ * N_ * 4);
  float* gh   = (float*)take(B_ * N_ * 4);
  float* sr   = (float*)take(B_ * N_ * 4);
  float* dA   = (float*)take(64);
  float* dBzr = (float*)take(64);
  float* dBh  = (float*)take(64);
  float* csr  = (float*)take(64);
  if (off > ws_size) return;  // workspace too small (needs ~142 MB)

  float* mu_out = (float*)d_out;
  float* SigOut = (float*)d_out + (size_t)B_ * N_;
  // bf16 copies of the two big f32 inputs live in SigOut's dead region
  // (fully overwritten by the h-gate stage-2 + combine at the end).
  unsigned short* SinH = (unsigned short*)SigOut;                 // 32 MB
  unsigned short* SstH = (unsigned short*)SigOut + (size_t)B_ * NN_; // 32 MB

  const unsigned short* ATz = AT;
  const unsigned short* ATr = AT + (size_t)N_ * 2048;
  const unsigned short* ATh = AT + (size_t)2 * N_ * 2048;

  // ---- prep ----
  conv_bf16<<<2048, 256, 0, stream>>>(sin_, SinH, B_ * NN_ / 4);
  conv_bf16<<<2048, 256, 0, stream>>>(Sst,  SstH, B_ * NN_ / 4);
  softplus6<<<6, 256, 0, stream>>>(uzs, wzs, urs, wrs, uhs, whs, sp);
  scalars1<<<16, 256, 0, stream>>>(mu, prev, sin_, Sst, dA, dBzr);
  build_AT<<<dim3(32, 64, 3), 256, 0, stream>>>(Uz, Wz, Ur, Wr, Uh, Wh, AT);
  gate_pre2<<<dim3(64, 8, 2), 256, 0, stream>>>(mu, prev, Uz, Wz, Ur, Wr, Ppart);
  gate_act2<<<64, 256, 0, stream>>>(Ppart, z, gz, rr, gr);
  sr_csr<<<16, 256, 0, stream>>>(prev, rr, sr, csr);
  gate_pre1<<<dim3(64, 8), 256, 0, stream>>>(mu, sr, Uh, Wh, Ppart);
  gate_act1<<<64, 256, 0, stream>>>(Ppart, h, gh);

  const dim3 gg1(8, 4, 16);   // paired stage-1
  const dim3 gg2(4, 4, 16);   // stage-2
  const long tS = (long)2048 * 1024;

  // ---- z gate ----
  gemm256<0, 1><<<gg1, 512, 0, stream>>>(ATz, 2048, 0, 0, SinH, SstH, 1024, (long)NN_, 1024,
                                         Tcm, 2048, tS, 0, nullptr, nullptr, nullptr, nullptr, nullptr);
  gemm256<1, 0><<<gg2, 512, 0, stream>>>(ATz, 2048, 0, 0, Tcm, nullptr, 2048, tS, 2048,
                                         Sz, 1024, (long)NN_, 0, gz, sp + 0, sp + 1024, dA, dBzr);
  // ---- r gate ----
  gemm256<0, 1><<<gg1, 512, 0, stream>>>(ATr, 2048, 0, 0, SinH, SstH, 1024, (long)NN_, 1024,
                                         Tcm, 2048, tS, 0, nullptr, nullptr, nullptr, nullptr, nullptr);
  gemm256<1, 0><<<gg2, 512, 0, stream>>>(ATr, 2048, 0, 0, Tcm, nullptr, 2048, tS, 2048,
                                         Sg, 1024, (long)NN_, 0, gr, sp + 2048, sp + 3072, dA, dBzr);
  // ---- sigma_g (in place over Sg) ----
  hadamard_sg<<<16384, 256, 0, stream>>>(Sst, Sg, prev, rr);
  scalars2<<<16, 256, 0, stream>>>(Sg, csr, dBh);
  // ---- h gate ----
  gemm256<0, 1><<<gg1, 512, 0, stream>>>(ATh, 2048, 0, 0, SinH, Sg, 1024, (long)NN_, 1024,
                                         Tcm, 2048, tS, 0, nullptr, nullptr, nullptr, nullptr, nullptr);
  gemm256<2, 0><<<gg2, 512, 0, stream>>>(ATh, 2048, 0, 0, Tcm, nullptr, 2048, tS, 2048,
                                         SigOut, 1024, (long)NN_, 0, gh, sp + 4096, sp + 5120, dA, dBh);
  // ---- combine ----
  mu_kernel<<<64, 256, 0, stream>>>(z, prev, h, mu_out);
  combine<<<16384, 256, 0, stream>>>(Sz, Sst, z, prev, h, SigOut);
}